// Round 11
// baseline (133.154 us; speedup 1.0000x reference)
//
#include <hip/hip_runtime.h>
#include <stdint.h>
#include <stddef.h>

typedef __attribute__((ext_vector_type(8))) short short8;
typedef __attribute__((ext_vector_type(4))) float f32x4;

__device__ inline unsigned short f2bf(float x) {
    unsigned u = __float_as_uint(x);
    unsigned r = (u + 0x7fffu + ((u >> 16) & 1u)) >> 16;
    return (unsigned short)r;
}

// ---------------- K1: node = mean(tf, axis=-1) ----------------
// MEASURED (R10 probe): ~40 us, ~6.7 TB/s = at HBM floor. Do not touch.
__global__ __launch_bounds__(256) void k1_mean(const float* __restrict__ tf,
                                               float* __restrict__ node) {
    int wave = (blockIdx.x * blockDim.x + threadIdx.x) >> 6;  // 0..32767
    int lane = threadIdx.x & 63;
    int half = lane >> 5;
    int c = lane & 31;
    const f32x4* tf4 = reinterpret_cast<const f32x4*>(tf);
    size_t base = (size_t)wave * 8 * 64;

    f32x4 v[8];
#pragma unroll
    for (int k = 0; k < 8; ++k) v[k] = __builtin_nontemporal_load(&tf4[base + (size_t)k * 64 + lane]);

    float s[8];
#pragma unroll
    for (int k = 0; k < 8; ++k) s[k] = (v[k][0] + v[k][1]) + (v[k][2] + v[k][3]);
#pragma unroll
    for (int m = 1; m <= 16; m <<= 1) {
#pragma unroll
        for (int k = 0; k < 8; ++k) s[k] += __shfl_xor(s[k], m);
    }
    if (c == 0) {
#pragma unroll
        for (int k = 0; k < 8; ++k) {
            int rp = wave * 8 + k;
            node[(size_t)rp * 2 + half] = s[k] * (1.0f / 128.0f);
        }
    }
}

// ---------------- K2: pi = node@Wi + b1, pj = node@Wj (MFMA) ----------------
__global__ __launch_bounds__(256) void k2_proj(const float* __restrict__ node,
                                               const float* __restrict__ W1,
                                               const float* __restrict__ b1,
                                               float* __restrict__ pi,
                                               float* __restrict__ pj) {
    const int LP = 136;
    __shared__ unsigned short A_lds[32 * LP];
    __shared__ unsigned short BT[128 * LP];
    __shared__ float b1s[128];

    int tid = threadIdx.x;
    int rblk = blockIdx.x >> 1;
    int half = blockIdx.x & 1;
    int r0 = rblk * 32;

    {
        int row = tid >> 3;
        int c0 = (tid & 7) * 16;
        const float4* src = reinterpret_cast<const float4*>(node + (size_t)(r0 + row) * 128 + c0);
        short8 pk[2];
#pragma unroll
        for (int q = 0; q < 2; ++q) {
            float4 va = src[q * 2 + 0];
            float4 vb = src[q * 2 + 1];
            pk[q][0] = (short)f2bf(va.x); pk[q][1] = (short)f2bf(va.y);
            pk[q][2] = (short)f2bf(va.z); pk[q][3] = (short)f2bf(va.w);
            pk[q][4] = (short)f2bf(vb.x); pk[q][5] = (short)f2bf(vb.y);
            pk[q][6] = (short)f2bf(vb.z); pk[q][7] = (short)f2bf(vb.w);
        }
        short8* dst = reinterpret_cast<short8*>(&A_lds[row * LP + c0]);
        dst[0] = pk[0];
        dst[1] = pk[1];
    }
    {
        int n = tid & 127;
        int kh = tid >> 7;
        const float* Wbase = W1 + (size_t)half * 128 * 128 + n;
#pragma unroll
        for (int g = 0; g < 8; ++g) {
            int kb = kh * 64 + g * 8;
            short8 pk;
#pragma unroll
            for (int e = 0; e < 8; ++e) pk[e] = (short)f2bf(Wbase[(size_t)(kb + e) * 128]);
            *reinterpret_cast<short8*>(&BT[n * LP + kb]) = pk;
        }
    }
    if (tid < 128) b1s[tid] = b1[tid];
    __syncthreads();

    int w = tid >> 6;
    int l = tid & 63;
    int lr = l & 15;
    int lg = l >> 4;
    int rt = w & 1;
    int ch = w >> 1;

    f32x4 acc[4] = {{0,0,0,0},{0,0,0,0},{0,0,0,0},{0,0,0,0}};
#pragma unroll
    for (int ks = 0; ks < 4; ++ks) {
        int kb = ks * 32 + lg * 8;
        short8 afrag = *reinterpret_cast<const short8*>(&A_lds[(rt * 16 + lr) * LP + kb]);
#pragma unroll
        for (int nt = 0; nt < 4; ++nt) {
            short8 bfrag = *reinterpret_cast<const short8*>(&BT[(ch * 64 + nt * 16 + lr) * LP + kb]);
            acc[nt] = __builtin_amdgcn_mfma_f32_16x16x32_bf16(afrag, bfrag, acc[nt], 0, 0, 0);
        }
    }
    float* out = half ? pj : pi;
#pragma unroll
    for (int nt = 0; nt < 4; ++nt) {
        int col = ch * 64 + nt * 16 + lr;
        float bias = half ? 0.0f : b1s[col];
#pragma unroll
        for (int r = 0; r < 4; ++r) {
            int row = r0 + rt * 16 + lg * 4 + r;
            out[(size_t)row * 128 + col] = acc[nt][r] + bias;
        }
    }
}

// ---------------- K3: pairwise MLP via MFMA ----------------
// NOTE: launched x4 this round as a timing probe (idempotent).
__global__ __launch_bounds__(256) void k3_mlp(const float* __restrict__ pi,
                                              const float* __restrict__ pj,
                                              const float* __restrict__ W2,
                                              const float* __restrict__ b2,
                                              const float* __restrict__ W3,
                                              const float* __restrict__ b3,
                                              float* __restrict__ F) {
    const int LDA = 136;
    __shared__ unsigned short A_lds[64 * LDA];
    __shared__ unsigned short W2T[64 * LDA];
    __shared__ float pipb4[4][128];
    __shared__ float b2s[64], w3s[64];

    int tid = threadIdx.x;
    int b = blockIdx.x >> 4;
    int it = blockIdx.x & 15;
    int i0 = it * 4;
    int jt = tid >> 2;
    int kq = tid & 3;

    float pjreg[32];
    {
        const float* src = pj + ((size_t)(b * 64 + jt) * 128 + kq * 32);
#pragma unroll
        for (int e = 0; e < 8; ++e) {
            float4 v = reinterpret_cast<const float4*>(src)[e];
            pjreg[e * 4 + 0] = v.x;
            pjreg[e * 4 + 1] = v.y;
            pjreg[e * 4 + 2] = v.z;
            pjreg[e * 4 + 3] = v.w;
        }
    }
    if (tid < 128) {
        int row = tid >> 5;
        int c4 = tid & 31;
        float4 v = reinterpret_cast<const float4*>(pi + ((size_t)(b * 64 + i0 + row) * 128))[c4];
        reinterpret_cast<float4*>(&pipb4[row][0])[c4] = v;
    }
    {
        int m = jt;
        for (int e = 0; e < 32; ++e) {
            int k = kq * 32 + e;
            W2T[m * LDA + k] = f2bf(W2[(size_t)k * 64 + m]);
        }
    }
    if (tid < 64) {
        b2s[tid] = b2[tid];
        w3s[tid] = W3[tid];
    }
    float b3v = b3[0];
    __syncthreads();

    int w = tid >> 6;
    int l = tid & 63;
    int lr = l & 15;
    int lg = l >> 4;

    for (int il = 0; il < 4; ++il) {
        {
            unsigned* dst = reinterpret_cast<unsigned*>(&A_lds[jt * LDA + kq * 32]);
#pragma unroll
            for (int e2 = 0; e2 < 16; ++e2) {
                float a0 = pipb4[il][kq * 32 + e2 * 2 + 0] + pjreg[e2 * 2 + 0];
                float a1 = pipb4[il][kq * 32 + e2 * 2 + 1] + pjreg[e2 * 2 + 1];
                a0 = fmaxf(a0, 0.0f);
                a1 = fmaxf(a1, 0.0f);
                dst[e2] = (unsigned)f2bf(a0) | ((unsigned)f2bf(a1) << 16);
            }
        }
        __syncthreads();
        f32x4 acc0 = {0.f, 0.f, 0.f, 0.f};
        f32x4 acc1 = {0.f, 0.f, 0.f, 0.f};
        f32x4 acc2 = {0.f, 0.f, 0.f, 0.f};
        f32x4 acc3 = {0.f, 0.f, 0.f, 0.f};
#pragma unroll
        for (int ks = 0; ks < 4; ++ks) {
            int kb = ks * 32 + lg * 8;
            short8 afrag = *reinterpret_cast<const short8*>(&A_lds[(w * 16 + lr) * LDA + kb]);
            short8 b0 = *reinterpret_cast<const short8*>(&W2T[(0 * 16 + lr) * LDA + kb]);
            short8 b1f = *reinterpret_cast<const short8*>(&W2T[(1 * 16 + lr) * LDA + kb]);
            short8 b2f = *reinterpret_cast<const short8*>(&W2T[(2 * 16 + lr) * LDA + kb]);
            short8 b3f = *reinterpret_cast<const short8*>(&W2T[(3 * 16 + lr) * LDA + kb]);
            acc0 = __builtin_amdgcn_mfma_f32_16x16x32_bf16(afrag, b0, acc0, 0, 0, 0);
            acc1 = __builtin_amdgcn_mfma_f32_16x16x32_bf16(afrag, b1f, acc1, 0, 0, 0);
            acc2 = __builtin_amdgcn_mfma_f32_16x16x32_bf16(afrag, b2f, acc2, 0, 0, 0);
            acc3 = __builtin_amdgcn_mfma_f32_16x16x32_bf16(afrag, b3f, acc3, 0, 0, 0);
        }
        float part[4] = {0.f, 0.f, 0.f, 0.f};
#pragma unroll
        for (int mt = 0; mt < 4; ++mt) {
            int m = mt * 16 + lr;
            float w3 = w3s[m];
            float bb = b2s[m];
            f32x4 a = (mt == 0) ? acc0 : (mt == 1) ? acc1 : (mt == 2) ? acc2 : acc3;
#pragma unroll
            for (int r = 0; r < 4; ++r) {
                float h = fmaxf(a[r] + bb, 0.0f);
                part[r] += h * w3;
            }
        }
#pragma unroll
        for (int r = 0; r < 4; ++r) {
            part[r] += __shfl_xor(part[r], 1);
            part[r] += __shfl_xor(part[r], 2);
            part[r] += __shfl_xor(part[r], 4);
            part[r] += __shfl_xor(part[r], 8);
        }
        if (lr == 0) {
#pragma unroll
            for (int r = 0; r < 4; ++r) {
                int j = w * 16 + lg * 4 + r;
                F[((size_t)b * 64 + i0 + il) * 64 + j] = part[r] + b3v;
            }
        }
        __syncthreads();
    }
}

// ---------------- K4: symmetrize + eye + row-normalize ----------------
__global__ __launch_bounds__(256) void k4_final(const float* __restrict__ F,
                                                const float* __restrict__ ap,
                                                float* __restrict__ out) {
    __shared__ float s[64][65];
    int b = blockIdx.x;
    int tid = threadIdx.x;
    for (int idx = tid; idx < 4096; idx += 256) {
        s[idx >> 6][idx & 63] = F[(size_t)b * 4096 + idx];
    }
    __syncthreads();
    int w = tid >> 6, lane = tid & 63;
#pragma unroll
    for (int itr = 0; itr < 16; ++itr) {
        int i = w + 4 * itr;
        float a_ij = ap[i * 64 + lane];
        float v = 0.5f * a_ij + 0.25f * (s[i][lane] + s[lane][i]);
        v = fmaxf(v, 0.0f);
        if (i == lane) v += 1.0f;
        float sum = v;
        sum += __shfl_xor(sum, 1);
        sum += __shfl_xor(sum, 2);
        sum += __shfl_xor(sum, 4);
        sum += __shfl_xor(sum, 8);
        sum += __shfl_xor(sum, 16);
        sum += __shfl_xor(sum, 32);
        out[(size_t)b * 4096 + i * 64 + lane] = v / (sum + 1e-8f);
    }
}

extern "C" void kernel_launch(void* const* d_in, const int* in_sizes, int n_in,
                              void* d_out, int out_size, void* d_ws, size_t ws_size,
                              hipStream_t stream) {
    const float* tf = (const float*)d_in[0];
    const float* ap = (const float*)d_in[1];
    const float* W1 = (const float*)d_in[2];
    const float* b1 = (const float*)d_in[3];
    const float* W2 = (const float*)d_in[4];
    const float* b2 = (const float*)d_in[5];
    const float* W3 = (const float*)d_in[6];
    const float* b3 = (const float*)d_in[7];
    float* out = (float*)d_out;

    char* ws = (char*)d_ws;
    float* node = (float*)(ws);                          // 2 MB
    float* pi   = (float*)(ws + (size_t)(2 << 20));      // 2 MB (pi + b1)
    float* pj   = (float*)(ws + (size_t)(4 << 20));      // 2 MB
    float* F    = (float*)(ws + (size_t)(6 << 20));      // 1 MB

    k1_mean<<<8192, 256, 0, stream>>>(tf, node);
    k2_proj<<<256, 256, 0, stream>>>(node, W1, b1, pi, pj);
    // TIMING PROBE: k3 launched x4 (idempotent). (dur_us - 77)/3 ~= k3 + gap.
    k3_mlp<<<1024, 256, 0, stream>>>(pi, pj, W2, b2, W3, b3, F);
    k3_mlp<<<1024, 256, 0, stream>>>(pi, pj, W2, b2, W3, b3, F);
    k3_mlp<<<1024, 256, 0, stream>>>(pi, pj, W2, b2, W3, b3, F);
    k3_mlp<<<1024, 256, 0, stream>>>(pi, pj, W2, b2, W3, b3, F);
    k4_final<<<64, 256, 0, stream>>>(F, ap, out);
}

// Round 12
// 73.881 us; speedup vs baseline: 1.8023x; 1.8023x over previous
//
#include <hip/hip_runtime.h>
#include <stdint.h>
#include <stddef.h>

typedef __attribute__((ext_vector_type(8))) short short8;
typedef __attribute__((ext_vector_type(4))) float f32x4;
typedef __attribute__((ext_vector_type(4))) unsigned uint4v;

__device__ inline unsigned short f2bf(float x) {
    unsigned u = __float_as_uint(x);
    unsigned r = (u + 0x7fffu + ((u >> 16) & 1u)) >> 16;
    return (unsigned short)r;
}

// ---------------- K1: node = mean(tf, axis=-1) ----------------
// MEASURED (R10 probe): ~40 us, ~6.7 TB/s = at HBM floor. Do not touch.
__global__ __launch_bounds__(256) void k1_mean(const float* __restrict__ tf,
                                               float* __restrict__ node) {
    int wave = (blockIdx.x * blockDim.x + threadIdx.x) >> 6;  // 0..32767
    int lane = threadIdx.x & 63;
    int half = lane >> 5;
    int c = lane & 31;
    const f32x4* tf4 = reinterpret_cast<const f32x4*>(tf);
    size_t base = (size_t)wave * 8 * 64;

    f32x4 v[8];
#pragma unroll
    for (int k = 0; k < 8; ++k) v[k] = __builtin_nontemporal_load(&tf4[base + (size_t)k * 64 + lane]);

    float s[8];
#pragma unroll
    for (int k = 0; k < 8; ++k) s[k] = (v[k][0] + v[k][1]) + (v[k][2] + v[k][3]);
#pragma unroll
    for (int m = 1; m <= 16; m <<= 1) {
#pragma unroll
        for (int k = 0; k < 8; ++k) s[k] += __shfl_xor(s[k], m);
    }
    if (c == 0) {
#pragma unroll
        for (int k = 0; k < 8; ++k) {
            int rp = wave * 8 + k;
            node[(size_t)rp * 2 + half] = s[k] * (1.0f / 128.0f);
        }
    }
}

// ---------------- K2: pi = node@Wi + b1, pj = node@Wj (MFMA) ----------------
__global__ __launch_bounds__(256) void k2_proj(const float* __restrict__ node,
                                               const float* __restrict__ W1,
                                               const float* __restrict__ b1,
                                               float* __restrict__ pi,
                                               float* __restrict__ pj) {
    const int LP = 136;
    __shared__ unsigned short A_lds[32 * LP];
    __shared__ unsigned short BT[128 * LP];
    __shared__ float b1s[128];

    int tid = threadIdx.x;
    int rblk = blockIdx.x >> 1;
    int half = blockIdx.x & 1;
    int r0 = rblk * 32;

    {
        int row = tid >> 3;
        int c0 = (tid & 7) * 16;
        const float4* src = reinterpret_cast<const float4*>(node + (size_t)(r0 + row) * 128 + c0);
        short8 pk[2];
#pragma unroll
        for (int q = 0; q < 2; ++q) {
            float4 va = src[q * 2 + 0];
            float4 vb = src[q * 2 + 1];
            pk[q][0] = (short)f2bf(va.x); pk[q][1] = (short)f2bf(va.y);
            pk[q][2] = (short)f2bf(va.z); pk[q][3] = (short)f2bf(va.w);
            pk[q][4] = (short)f2bf(vb.x); pk[q][5] = (short)f2bf(vb.y);
            pk[q][6] = (short)f2bf(vb.z); pk[q][7] = (short)f2bf(vb.w);
        }
        short8* dst = reinterpret_cast<short8*>(&A_lds[row * LP + c0]);
        dst[0] = pk[0];
        dst[1] = pk[1];
    }
    {
        int n = tid & 127;
        int kh = tid >> 7;
        const float* Wbase = W1 + (size_t)half * 128 * 128 + n;
#pragma unroll
        for (int g = 0; g < 8; ++g) {
            int kb = kh * 64 + g * 8;
            short8 pk;
#pragma unroll
            for (int e = 0; e < 8; ++e) pk[e] = (short)f2bf(Wbase[(size_t)(kb + e) * 128]);
            *reinterpret_cast<short8*>(&BT[n * LP + kb]) = pk;
        }
    }
    if (tid < 128) b1s[tid] = b1[tid];
    __syncthreads();

    int w = tid >> 6;
    int l = tid & 63;
    int lr = l & 15;
    int lg = l >> 4;
    int rt = w & 1;
    int ch = w >> 1;

    f32x4 acc[4] = {{0,0,0,0},{0,0,0,0},{0,0,0,0},{0,0,0,0}};
#pragma unroll
    for (int ks = 0; ks < 4; ++ks) {
        int kb = ks * 32 + lg * 8;
        short8 afrag = *reinterpret_cast<const short8*>(&A_lds[(rt * 16 + lr) * LP + kb]);
#pragma unroll
        for (int nt = 0; nt < 4; ++nt) {
            short8 bfrag = *reinterpret_cast<const short8*>(&BT[(ch * 64 + nt * 16 + lr) * LP + kb]);
            acc[nt] = __builtin_amdgcn_mfma_f32_16x16x32_bf16(afrag, bfrag, acc[nt], 0, 0, 0);
        }
    }
    float* out = half ? pj : pi;
#pragma unroll
    for (int nt = 0; nt < 4; ++nt) {
        int col = ch * 64 + nt * 16 + lr;
        float bias = half ? 0.0f : b1s[col];
#pragma unroll
        for (int r = 0; r < 4; ++r) {
            int row = r0 + rt * 16 + lg * 4 + r;
            out[(size_t)row * 128 + col] = acc[nt][r] + bias;
        }
    }
}

// ---------------- K3: pairwise MLP via MFMA (reg-built A fragments) --------
// block = (b, i-tile of 4), 256 threads = 4 waves. Lane l of wave w owns
// MFMA A-row j = w*16 + (l&15), cols (l>>4)*8 + ks*32. pj cols for that
// (j, col-slice) staged in 32 regs at block start; pi cols read from LDS
// (broadcast b128). A fragment built IN REGISTERS -> no A_lds, no
// per-iteration barriers. W2T nt=0,1 fragments hoisted (32 VGPR).
__global__ __launch_bounds__(256) void k3_mlp(const float* __restrict__ pi,
                                              const float* __restrict__ pj,
                                              const float* __restrict__ W2,
                                              const float* __restrict__ b2,
                                              const float* __restrict__ W3,
                                              const float* __restrict__ b3,
                                              float* __restrict__ F) {
    const int LDA = 136;
    __shared__ unsigned short W2T[64 * LDA];
    __shared__ float pipb4[4][128];
    __shared__ float b2s[64], w3s[64];

    int tid = threadIdx.x;
    int b = blockIdx.x >> 4;
    int it = blockIdx.x & 15;
    int i0 = it * 4;
    int jt = tid >> 2;
    int kq = tid & 3;

    int w = tid >> 6;
    int l = tid & 63;
    int lr = l & 15;
    int lg = l >> 4;

    // pj slice for this lane's MFMA row: row j = w*16+lr, cols ks*32+lg*8..+8
    float pjreg[32];
    {
        const float* pjrow = pj + (size_t)(b * 64 + w * 16 + lr) * 128;
#pragma unroll
        for (int ks = 0; ks < 4; ++ks) {
            float4 q0 = *reinterpret_cast<const float4*>(pjrow + ks * 32 + lg * 8);
            float4 q1 = *reinterpret_cast<const float4*>(pjrow + ks * 32 + lg * 8 + 4);
            pjreg[ks * 8 + 0] = q0.x; pjreg[ks * 8 + 1] = q0.y;
            pjreg[ks * 8 + 2] = q0.z; pjreg[ks * 8 + 3] = q0.w;
            pjreg[ks * 8 + 4] = q1.x; pjreg[ks * 8 + 5] = q1.y;
            pjreg[ks * 8 + 6] = q1.z; pjreg[ks * 8 + 7] = q1.w;
        }
    }
    // pi rows i0..i0+3 -> LDS (f32)
    if (tid < 128) {
        int row = tid >> 5;
        int c4 = tid & 31;
        float4 v = reinterpret_cast<const float4*>(pi + ((size_t)(b * 64 + i0 + row) * 128))[c4];
        reinterpret_cast<float4*>(&pipb4[row][0])[c4] = v;
    }
    // W2T[m][k] = W2[k][m], vectorized b128 writes
    {
        int m = jt;
#pragma unroll
        for (int g = 0; g < 4; ++g) {
            unsigned wb[4];
#pragma unroll
            for (int p = 0; p < 4; ++p) {
                int k = kq * 32 + g * 8 + p * 2;
                wb[p] = (unsigned)f2bf(W2[(size_t)k * 64 + m]) |
                        ((unsigned)f2bf(W2[(size_t)(k + 1) * 64 + m]) << 16);
            }
            *reinterpret_cast<uint4v*>(&W2T[m * LDA + kq * 32 + g * 8]) = *reinterpret_cast<uint4v*>(wb);
        }
    }
    if (tid < 64) {
        b2s[tid] = b2[tid];
        w3s[tid] = W3[tid];
    }
    float b3v = b3[0];
    __syncthreads();  // the only barrier

    // Hoist W2T fragments for nt=0,1 (iteration-invariant): 32 VGPR
    short8 bfr0[4], bfr1[4];
#pragma unroll
    for (int ks = 0; ks < 4; ++ks) {
        int kb = ks * 32 + lg * 8;
        bfr0[ks] = *reinterpret_cast<const short8*>(&W2T[(0 * 16 + lr) * LDA + kb]);
        bfr1[ks] = *reinterpret_cast<const short8*>(&W2T[(1 * 16 + lr) * LDA + kb]);
    }

    for (int il = 0; il < 4; ++il) {
        f32x4 acc0 = {0.f, 0.f, 0.f, 0.f};
        f32x4 acc1 = {0.f, 0.f, 0.f, 0.f};
        f32x4 acc2 = {0.f, 0.f, 0.f, 0.f};
        f32x4 acc3 = {0.f, 0.f, 0.f, 0.f};
        const float4* prow = reinterpret_cast<const float4*>(&pipb4[il][0]);
#pragma unroll
        for (int ks = 0; ks < 4; ++ks) {
            int kb = ks * 32 + lg * 8;
            // pi cols (broadcast within 16-lane group) + pj regs -> A fragment
            float4 pa = prow[ks * 8 + lg * 2];
            float4 pb = prow[ks * 8 + lg * 2 + 1];
            short8 afrag;
            afrag[0] = (short)f2bf(fmaxf(pa.x + pjreg[ks * 8 + 0], 0.0f));
            afrag[1] = (short)f2bf(fmaxf(pa.y + pjreg[ks * 8 + 1], 0.0f));
            afrag[2] = (short)f2bf(fmaxf(pa.z + pjreg[ks * 8 + 2], 0.0f));
            afrag[3] = (short)f2bf(fmaxf(pa.w + pjreg[ks * 8 + 3], 0.0f));
            afrag[4] = (short)f2bf(fmaxf(pb.x + pjreg[ks * 8 + 4], 0.0f));
            afrag[5] = (short)f2bf(fmaxf(pb.y + pjreg[ks * 8 + 5], 0.0f));
            afrag[6] = (short)f2bf(fmaxf(pb.z + pjreg[ks * 8 + 6], 0.0f));
            afrag[7] = (short)f2bf(fmaxf(pb.w + pjreg[ks * 8 + 7], 0.0f));
            short8 b2f = *reinterpret_cast<const short8*>(&W2T[(2 * 16 + lr) * LDA + kb]);
            short8 b3f = *reinterpret_cast<const short8*>(&W2T[(3 * 16 + lr) * LDA + kb]);
            acc0 = __builtin_amdgcn_mfma_f32_16x16x32_bf16(afrag, bfr0[ks], acc0, 0, 0, 0);
            acc1 = __builtin_amdgcn_mfma_f32_16x16x32_bf16(afrag, bfr1[ks], acc1, 0, 0, 0);
            acc2 = __builtin_amdgcn_mfma_f32_16x16x32_bf16(afrag, b2f, acc2, 0, 0, 0);
            acc3 = __builtin_amdgcn_mfma_f32_16x16x32_bf16(afrag, b3f, acc3, 0, 0, 0);
        }
        // feat = sum_m relu(C + b2[m]) * W3[m]; C: col(m)=lane&15, row(j)=(lane>>4)*4+r
        float part[4] = {0.f, 0.f, 0.f, 0.f};
#pragma unroll
        for (int mt = 0; mt < 4; ++mt) {
            int m = mt * 16 + lr;
            float w3 = w3s[m];
            float bb = b2s[m];
            f32x4 a = (mt == 0) ? acc0 : (mt == 1) ? acc1 : (mt == 2) ? acc2 : acc3;
#pragma unroll
            for (int r = 0; r < 4; ++r) {
                float h = fmaxf(a[r] + bb, 0.0f);
                part[r] += h * w3;
            }
        }
#pragma unroll
        for (int r = 0; r < 4; ++r) {
            part[r] += __shfl_xor(part[r], 1);
            part[r] += __shfl_xor(part[r], 2);
            part[r] += __shfl_xor(part[r], 4);
            part[r] += __shfl_xor(part[r], 8);
        }
        if (lr == 0) {
#pragma unroll
            for (int r = 0; r < 4; ++r) {
                int j = w * 16 + lg * 4 + r;
                F[((size_t)b * 64 + i0 + il) * 64 + j] = part[r] + b3v;
            }
        }
    }
}

// ---------------- K4: symmetrize + eye + row-normalize ----------------
__global__ __launch_bounds__(256) void k4_final(const float* __restrict__ F,
                                                const float* __restrict__ ap,
                                                float* __restrict__ out) {
    __shared__ float s[64][65];
    int b = blockIdx.x;
    int tid = threadIdx.x;
    for (int idx = tid; idx < 4096; idx += 256) {
        s[idx >> 6][idx & 63] = F[(size_t)b * 4096 + idx];
    }
    __syncthreads();
    int w = tid >> 6, lane = tid & 63;
#pragma unroll
    for (int itr = 0; itr < 16; ++itr) {
        int i = w + 4 * itr;
        float a_ij = ap[i * 64 + lane];
        float v = 0.5f * a_ij + 0.25f * (s[i][lane] + s[lane][i]);
        v = fmaxf(v, 0.0f);
        if (i == lane) v += 1.0f;
        float sum = v;
        sum += __shfl_xor(sum, 1);
        sum += __shfl_xor(sum, 2);
        sum += __shfl_xor(sum, 4);
        sum += __shfl_xor(sum, 8);
        sum += __shfl_xor(sum, 16);
        sum += __shfl_xor(sum, 32);
        out[(size_t)b * 4096 + i * 64 + lane] = v / (sum + 1e-8f);
    }
}

extern "C" void kernel_launch(void* const* d_in, const int* in_sizes, int n_in,
                              void* d_out, int out_size, void* d_ws, size_t ws_size,
                              hipStream_t stream) {
    const float* tf = (const float*)d_in[0];
    const float* ap = (const float*)d_in[1];
    const float* W1 = (const float*)d_in[2];
    const float* b1 = (const float*)d_in[3];
    const float* W2 = (const float*)d_in[4];
    const float* b2 = (const float*)d_in[5];
    const float* W3 = (const float*)d_in[6];
    const float* b3 = (const float*)d_in[7];
    float* out = (float*)d_out;

    char* ws = (char*)d_ws;
    float* node = (float*)(ws);                          // 2 MB
    float* pi   = (float*)(ws + (size_t)(2 << 20));      // 2 MB (pi + b1)
    float* pj   = (float*)(ws + (size_t)(4 << 20));      // 2 MB
    float* F    = (float*)(ws + (size_t)(6 << 20));      // 1 MB

    k1_mean<<<8192, 256, 0, stream>>>(tf, node);
    k2_proj<<<256, 256, 0, stream>>>(node, W1, b1, pi, pj);
    k3_mlp<<<1024, 256, 0, stream>>>(pi, pj, W2, b2, W3, b3, F);
    k4_final<<<64, 256, 0, stream>>>(F, ap, out);
}

// Round 13
// 71.756 us; speedup vs baseline: 1.8557x; 1.0296x over previous
//
#include <hip/hip_runtime.h>
#include <stdint.h>
#include <stddef.h>

typedef __attribute__((ext_vector_type(8))) short short8;
typedef __attribute__((ext_vector_type(4))) float f32x4;
typedef __attribute__((ext_vector_type(4))) unsigned uint4v;

__device__ inline unsigned short f2bf(float x) {
    unsigned u = __float_as_uint(x);
    unsigned r = (u + 0x7fffu + ((u >> 16) & 1u)) >> 16;
    return (unsigned short)r;
}

// ---------------- K1: node = mean(tf, axis=-1) ----------------
// MEASURED (R10 probe): ~40 us, ~6.7 TB/s = at HBM floor. Do not touch.
__global__ __launch_bounds__(256) void k1_mean(const float* __restrict__ tf,
                                               float* __restrict__ node) {
    int wave = (blockIdx.x * blockDim.x + threadIdx.x) >> 6;  // 0..32767
    int lane = threadIdx.x & 63;
    int half = lane >> 5;
    int c = lane & 31;
    const f32x4* tf4 = reinterpret_cast<const f32x4*>(tf);
    size_t base = (size_t)wave * 8 * 64;

    f32x4 v[8];
#pragma unroll
    for (int k = 0; k < 8; ++k) v[k] = __builtin_nontemporal_load(&tf4[base + (size_t)k * 64 + lane]);

    float s[8];
#pragma unroll
    for (int k = 0; k < 8; ++k) s[k] = (v[k][0] + v[k][1]) + (v[k][2] + v[k][3]);
#pragma unroll
    for (int m = 1; m <= 16; m <<= 1) {
#pragma unroll
        for (int k = 0; k < 8; ++k) s[k] += __shfl_xor(s[k], m);
    }
    if (c == 0) {
#pragma unroll
        for (int k = 0; k < 8; ++k) {
            int rp = wave * 8 + k;
            node[(size_t)rp * 2 + half] = s[k] * (1.0f / 128.0f);
        }
    }
}

// ---------------- K2: pi = node@Wi + b1, pj = node@Wj (MFMA) ----------------
// 512 threads (8 waves) per block for latency hiding; 256 blocks.
// MEASURED (ledger R10-R12): k2+k4 ~ 16 us combined -> occupancy-starved.
__global__ __launch_bounds__(512) void k2_proj(const float* __restrict__ node,
                                               const float* __restrict__ W1,
                                               const float* __restrict__ b1,
                                               float* __restrict__ pi,
                                               float* __restrict__ pj) {
    const int LP = 136;
    __shared__ unsigned short A_lds[32 * LP];
    __shared__ unsigned short BT[128 * LP];
    __shared__ float b1s[128];

    int tid = threadIdx.x;
    int rblk = blockIdx.x >> 1;
    int half = blockIdx.x & 1;
    int r0 = rblk * 32;

    // Stage A: 32 rows x 128 cols; thread -> row = tid>>4, 8 cols
    {
        int row = tid >> 4;
        int c0 = (tid & 15) * 8;
        const float4* src = reinterpret_cast<const float4*>(node + (size_t)(r0 + row) * 128 + c0);
        float4 va = src[0];
        float4 vb = src[1];
        short8 pk;
        pk[0] = (short)f2bf(va.x); pk[1] = (short)f2bf(va.y);
        pk[2] = (short)f2bf(va.z); pk[3] = (short)f2bf(va.w);
        pk[4] = (short)f2bf(vb.x); pk[5] = (short)f2bf(vb.y);
        pk[6] = (short)f2bf(vb.z); pk[7] = (short)f2bf(vb.w);
        *reinterpret_cast<short8*>(&A_lds[row * LP + c0]) = pk;
    }
    // Stage BT: n = tid&127, k-quarter kq = tid>>7 (32 k's each)
    {
        int n = tid & 127;
        int kq = tid >> 7;
        const float* Wbase = W1 + (size_t)half * 128 * 128 + n;
#pragma unroll
        for (int g = 0; g < 4; ++g) {
            int kb = kq * 32 + g * 8;
            short8 pk;
#pragma unroll
            for (int e = 0; e < 8; ++e) pk[e] = (short)f2bf(Wbase[(size_t)(kb + e) * 128]);
            *reinterpret_cast<short8*>(&BT[n * LP + kb]) = pk;
        }
    }
    if (tid < 128) b1s[tid] = b1[tid];
    __syncthreads();

    int w = tid >> 6;      // 0..7
    int l = tid & 63;
    int lr = l & 15;
    int lg = l >> 4;
    int rt = w & 1;        // row-tile of 16
    int cq = w >> 1;       // col-quarter of 32

    f32x4 acc[2] = {{0, 0, 0, 0}, {0, 0, 0, 0}};
#pragma unroll
    for (int ks = 0; ks < 4; ++ks) {
        int kb = ks * 32 + lg * 8;
        short8 afrag = *reinterpret_cast<const short8*>(&A_lds[(rt * 16 + lr) * LP + kb]);
#pragma unroll
        for (int nt = 0; nt < 2; ++nt) {
            short8 bfrag = *reinterpret_cast<const short8*>(&BT[(cq * 32 + nt * 16 + lr) * LP + kb]);
            acc[nt] = __builtin_amdgcn_mfma_f32_16x16x32_bf16(afrag, bfrag, acc[nt], 0, 0, 0);
        }
    }
    float* out = half ? pj : pi;
#pragma unroll
    for (int nt = 0; nt < 2; ++nt) {
        int col = cq * 32 + nt * 16 + lr;
        float bias = half ? 0.0f : b1s[col];
#pragma unroll
        for (int r = 0; r < 4; ++r) {
            int row = r0 + rt * 16 + lg * 4 + r;
            out[(size_t)row * 128 + col] = acc[nt][r] + bias;
        }
    }
}

// ---------------- K3: pairwise MLP via MFMA (reg-built A fragments) --------
__global__ __launch_bounds__(256) void k3_mlp(const float* __restrict__ pi,
                                              const float* __restrict__ pj,
                                              const float* __restrict__ W2,
                                              const float* __restrict__ b2,
                                              const float* __restrict__ W3,
                                              const float* __restrict__ b3,
                                              float* __restrict__ F) {
    const int LDA = 136;
    __shared__ unsigned short W2T[64 * LDA];
    __shared__ float pipb4[4][128];
    __shared__ float b2s[64], w3s[64];

    int tid = threadIdx.x;
    int b = blockIdx.x >> 4;
    int it = blockIdx.x & 15;
    int i0 = it * 4;
    int jt = tid >> 2;
    int kq = tid & 3;

    int w = tid >> 6;
    int l = tid & 63;
    int lr = l & 15;
    int lg = l >> 4;

    // pj slice for this lane's MFMA row: row j = w*16+lr, cols ks*32+lg*8..+8
    float pjreg[32];
    {
        const float* pjrow = pj + (size_t)(b * 64 + w * 16 + lr) * 128;
#pragma unroll
        for (int ks = 0; ks < 4; ++ks) {
            float4 q0 = *reinterpret_cast<const float4*>(pjrow + ks * 32 + lg * 8);
            float4 q1 = *reinterpret_cast<const float4*>(pjrow + ks * 32 + lg * 8 + 4);
            pjreg[ks * 8 + 0] = q0.x; pjreg[ks * 8 + 1] = q0.y;
            pjreg[ks * 8 + 2] = q0.z; pjreg[ks * 8 + 3] = q0.w;
            pjreg[ks * 8 + 4] = q1.x; pjreg[ks * 8 + 5] = q1.y;
            pjreg[ks * 8 + 6] = q1.z; pjreg[ks * 8 + 7] = q1.w;
        }
    }
    if (tid < 128) {
        int row = tid >> 5;
        int c4 = tid & 31;
        float4 v = reinterpret_cast<const float4*>(pi + ((size_t)(b * 64 + i0 + row) * 128))[c4];
        reinterpret_cast<float4*>(&pipb4[row][0])[c4] = v;
    }
    {
        int m = jt;
#pragma unroll
        for (int g = 0; g < 4; ++g) {
            unsigned wb[4];
#pragma unroll
            for (int p = 0; p < 4; ++p) {
                int k = kq * 32 + g * 8 + p * 2;
                wb[p] = (unsigned)f2bf(W2[(size_t)k * 64 + m]) |
                        ((unsigned)f2bf(W2[(size_t)(k + 1) * 64 + m]) << 16);
            }
            *reinterpret_cast<uint4v*>(&W2T[m * LDA + kq * 32 + g * 8]) = *reinterpret_cast<uint4v*>(wb);
        }
    }
    if (tid < 64) {
        b2s[tid] = b2[tid];
        w3s[tid] = W3[tid];
    }
    float b3v = b3[0];
    __syncthreads();

    short8 bfr0[4], bfr1[4];
#pragma unroll
    for (int ks = 0; ks < 4; ++ks) {
        int kb = ks * 32 + lg * 8;
        bfr0[ks] = *reinterpret_cast<const short8*>(&W2T[(0 * 16 + lr) * LDA + kb]);
        bfr1[ks] = *reinterpret_cast<const short8*>(&W2T[(1 * 16 + lr) * LDA + kb]);
    }

    for (int il = 0; il < 4; ++il) {
        f32x4 acc0 = {0.f, 0.f, 0.f, 0.f};
        f32x4 acc1 = {0.f, 0.f, 0.f, 0.f};
        f32x4 acc2 = {0.f, 0.f, 0.f, 0.f};
        f32x4 acc3 = {0.f, 0.f, 0.f, 0.f};
        const float4* prow = reinterpret_cast<const float4*>(&pipb4[il][0]);
#pragma unroll
        for (int ks = 0; ks < 4; ++ks) {
            int kb = ks * 32 + lg * 8;
            float4 pa = prow[ks * 8 + lg * 2];
            float4 pb = prow[ks * 8 + lg * 2 + 1];
            short8 afrag;
            afrag[0] = (short)f2bf(fmaxf(pa.x + pjreg[ks * 8 + 0], 0.0f));
            afrag[1] = (short)f2bf(fmaxf(pa.y + pjreg[ks * 8 + 1], 0.0f));
            afrag[2] = (short)f2bf(fmaxf(pa.z + pjreg[ks * 8 + 2], 0.0f));
            afrag[3] = (short)f2bf(fmaxf(pa.w + pjreg[ks * 8 + 3], 0.0f));
            afrag[4] = (short)f2bf(fmaxf(pb.x + pjreg[ks * 8 + 4], 0.0f));
            afrag[5] = (short)f2bf(fmaxf(pb.y + pjreg[ks * 8 + 5], 0.0f));
            afrag[6] = (short)f2bf(fmaxf(pb.z + pjreg[ks * 8 + 6], 0.0f));
            afrag[7] = (short)f2bf(fmaxf(pb.w + pjreg[ks * 8 + 7], 0.0f));
            short8 b2f = *reinterpret_cast<const short8*>(&W2T[(2 * 16 + lr) * LDA + kb]);
            short8 b3f = *reinterpret_cast<const short8*>(&W2T[(3 * 16 + lr) * LDA + kb]);
            acc0 = __builtin_amdgcn_mfma_f32_16x16x32_bf16(afrag, bfr0[ks], acc0, 0, 0, 0);
            acc1 = __builtin_amdgcn_mfma_f32_16x16x32_bf16(afrag, bfr1[ks], acc1, 0, 0, 0);
            acc2 = __builtin_amdgcn_mfma_f32_16x16x32_bf16(afrag, b2f, acc2, 0, 0, 0);
            acc3 = __builtin_amdgcn_mfma_f32_16x16x32_bf16(afrag, b3f, acc3, 0, 0, 0);
        }
        float part[4] = {0.f, 0.f, 0.f, 0.f};
#pragma unroll
        for (int mt = 0; mt < 4; ++mt) {
            int m = mt * 16 + lr;
            float w3 = w3s[m];
            float bb = b2s[m];
            f32x4 a = (mt == 0) ? acc0 : (mt == 1) ? acc1 : (mt == 2) ? acc2 : acc3;
#pragma unroll
            for (int r = 0; r < 4; ++r) {
                float h = fmaxf(a[r] + bb, 0.0f);
                part[r] += h * w3;
            }
        }
#pragma unroll
        for (int r = 0; r < 4; ++r) {
            part[r] += __shfl_xor(part[r], 1);
            part[r] += __shfl_xor(part[r], 2);
            part[r] += __shfl_xor(part[r], 4);
            part[r] += __shfl_xor(part[r], 8);
        }
        if (lr == 0) {
#pragma unroll
            for (int r = 0; r < 4; ++r) {
                int j = w * 16 + lg * 4 + r;
                F[((size_t)b * 64 + i0 + il) * 64 + j] = part[r] + b3v;
            }
        }
    }
}

// ---------------- K4: symmetrize + eye + row-normalize ----------------
// 1024 threads (16 waves) per block; wave handles 4 rows (was 16).
__global__ __launch_bounds__(1024) void k4_final(const float* __restrict__ F,
                                                 const float* __restrict__ ap,
                                                 float* __restrict__ out) {
    __shared__ float s[64][65];
    int b = blockIdx.x;
    int tid = threadIdx.x;
    for (int idx = tid; idx < 4096; idx += 1024) {
        s[idx >> 6][idx & 63] = F[(size_t)b * 4096 + idx];
    }
    __syncthreads();
    int wv = tid >> 6, lane = tid & 63;
#pragma unroll
    for (int itr = 0; itr < 4; ++itr) {
        int i = wv * 4 + itr;
        float a_ij = ap[i * 64 + lane];
        float v = 0.5f * a_ij + 0.25f * (s[i][lane] + s[lane][i]);
        v = fmaxf(v, 0.0f);
        if (i == lane) v += 1.0f;
        float sum = v;
        sum += __shfl_xor(sum, 1);
        sum += __shfl_xor(sum, 2);
        sum += __shfl_xor(sum, 4);
        sum += __shfl_xor(sum, 8);
        sum += __shfl_xor(sum, 16);
        sum += __shfl_xor(sum, 32);
        out[(size_t)b * 4096 + i * 64 + lane] = v / (sum + 1e-8f);
    }
}

extern "C" void kernel_launch(void* const* d_in, const int* in_sizes, int n_in,
                              void* d_out, int out_size, void* d_ws, size_t ws_size,
                              hipStream_t stream) {
    const float* tf = (const float*)d_in[0];
    const float* ap = (const float*)d_in[1];
    const float* W1 = (const float*)d_in[2];
    const float* b1 = (const float*)d_in[3];
    const float* W2 = (const float*)d_in[4];
    const float* b2 = (const float*)d_in[5];
    const float* W3 = (const float*)d_in[6];
    const float* b3 = (const float*)d_in[7];
    float* out = (float*)d_out;

    char* ws = (char*)d_ws;
    float* node = (float*)(ws);                          // 2 MB
    float* pi   = (float*)(ws + (size_t)(2 << 20));      // 2 MB (pi + b1)
    float* pj   = (float*)(ws + (size_t)(4 << 20));      // 2 MB
    float* F    = (float*)(ws + (size_t)(6 << 20));      // 1 MB

    k1_mean<<<8192, 256, 0, stream>>>(tf, node);
    k2_proj<<<256, 512, 0, stream>>>(node, W1, b1, pi, pj);
    k3_mlp<<<1024, 256, 0, stream>>>(pi, pj, W2, b2, W3, b3, F);
    k4_final<<<64, 1024, 0, stream>>>(F, ap, out);
}

// Round 14
// 70.827 us; speedup vs baseline: 1.8800x; 1.0131x over previous
//
#include <hip/hip_runtime.h>
#include <stdint.h>
#include <stddef.h>

typedef __attribute__((ext_vector_type(8))) short short8;
typedef __attribute__((ext_vector_type(4))) float f32x4;
typedef __attribute__((ext_vector_type(4))) unsigned uint4v;

__device__ inline unsigned short f2bf(float x) {
    unsigned u = __float_as_uint(x);
    unsigned r = (u + 0x7fffu + ((u >> 16) & 1u)) >> 16;
    return (unsigned short)r;
}

// Pack hi16(lo), hi16(hi) into one dword with a single v_perm_b32 (truncation).
__device__ inline unsigned pk2t(float lo, float hi) {
    return __builtin_amdgcn_perm(__float_as_uint(hi), __float_as_uint(lo), 0x07060302u);
}

// ---------------- K1: node = mean(tf, axis=-1) ----------------
// MEASURED (R10 probe): ~40 us, ~6.7 TB/s = at HBM floor. Do not touch.
__global__ __launch_bounds__(256) void k1_mean(const float* __restrict__ tf,
                                               float* __restrict__ node) {
    int wave = (blockIdx.x * blockDim.x + threadIdx.x) >> 6;  // 0..32767
    int lane = threadIdx.x & 63;
    int half = lane >> 5;
    int c = lane & 31;
    const f32x4* tf4 = reinterpret_cast<const f32x4*>(tf);
    size_t base = (size_t)wave * 8 * 64;

    f32x4 v[8];
#pragma unroll
    for (int k = 0; k < 8; ++k) v[k] = __builtin_nontemporal_load(&tf4[base + (size_t)k * 64 + lane]);

    float s[8];
#pragma unroll
    for (int k = 0; k < 8; ++k) s[k] = (v[k][0] + v[k][1]) + (v[k][2] + v[k][3]);
#pragma unroll
    for (int m = 1; m <= 16; m <<= 1) {
#pragma unroll
        for (int k = 0; k < 8; ++k) s[k] += __shfl_xor(s[k], m);
    }
    if (c == 0) {
#pragma unroll
        for (int k = 0; k < 8; ++k) {
            int rp = wave * 8 + k;
            node[(size_t)rp * 2 + half] = s[k] * (1.0f / 128.0f);
        }
    }
}

// ---------------- K2: pi = node@Wi + b1, pj = node@Wj (MFMA) ----------------
// 512 threads (8 waves) per block; 256 blocks.
__global__ __launch_bounds__(512) void k2_proj(const float* __restrict__ node,
                                               const float* __restrict__ W1,
                                               const float* __restrict__ b1,
                                               float* __restrict__ pi,
                                               float* __restrict__ pj) {
    const int LP = 136;
    __shared__ unsigned short A_lds[32 * LP];
    __shared__ unsigned short BT[128 * LP];
    __shared__ float b1s[128];

    int tid = threadIdx.x;
    int rblk = blockIdx.x >> 1;
    int half = blockIdx.x & 1;
    int r0 = rblk * 32;

    {
        int row = tid >> 4;
        int c0 = (tid & 15) * 8;
        const float4* src = reinterpret_cast<const float4*>(node + (size_t)(r0 + row) * 128 + c0);
        float4 va = src[0];
        float4 vb = src[1];
        short8 pk;
        pk[0] = (short)f2bf(va.x); pk[1] = (short)f2bf(va.y);
        pk[2] = (short)f2bf(va.z); pk[3] = (short)f2bf(va.w);
        pk[4] = (short)f2bf(vb.x); pk[5] = (short)f2bf(vb.y);
        pk[6] = (short)f2bf(vb.z); pk[7] = (short)f2bf(vb.w);
        *reinterpret_cast<short8*>(&A_lds[row * LP + c0]) = pk;
    }
    {
        int n = tid & 127;
        int kq = tid >> 7;
        const float* Wbase = W1 + (size_t)half * 128 * 128 + n;
#pragma unroll
        for (int g = 0; g < 4; ++g) {
            int kb = kq * 32 + g * 8;
            short8 pk;
#pragma unroll
            for (int e = 0; e < 8; ++e) pk[e] = (short)f2bf(Wbase[(size_t)(kb + e) * 128]);
            *reinterpret_cast<short8*>(&BT[n * LP + kb]) = pk;
        }
    }
    if (tid < 128) b1s[tid] = b1[tid];
    __syncthreads();

    int w = tid >> 6;
    int l = tid & 63;
    int lr = l & 15;
    int lg = l >> 4;
    int rt = w & 1;
    int cq = w >> 1;

    f32x4 acc[2] = {{0, 0, 0, 0}, {0, 0, 0, 0}};
#pragma unroll
    for (int ks = 0; ks < 4; ++ks) {
        int kb = ks * 32 + lg * 8;
        short8 afrag = *reinterpret_cast<const short8*>(&A_lds[(rt * 16 + lr) * LP + kb]);
#pragma unroll
        for (int nt = 0; nt < 2; ++nt) {
            short8 bfrag = *reinterpret_cast<const short8*>(&BT[(cq * 32 + nt * 16 + lr) * LP + kb]);
            acc[nt] = __builtin_amdgcn_mfma_f32_16x16x32_bf16(afrag, bfrag, acc[nt], 0, 0, 0);
        }
    }
    float* out = half ? pj : pi;
#pragma unroll
    for (int nt = 0; nt < 2; ++nt) {
        int col = cq * 32 + nt * 16 + lr;
        float bias = half ? 0.0f : b1s[col];
#pragma unroll
        for (int r = 0; r < 4; ++r) {
            int row = r0 + rt * 16 + lg * 4 + r;
            out[(size_t)row * 128 + col] = acc[nt][r] + bias;
        }
    }
}

// ---------------- K3: pairwise MLP via MFMA (reg-built A fragments) --------
// A-fragment convert/pack via single v_perm_b32 (truncation) -- hot path.
__global__ __launch_bounds__(256) void k3_mlp(const float* __restrict__ pi,
                                              const float* __restrict__ pj,
                                              const float* __restrict__ W2,
                                              const float* __restrict__ b2,
                                              const float* __restrict__ W3,
                                              const float* __restrict__ b3,
                                              float* __restrict__ F) {
    const int LDA = 136;
    __shared__ unsigned short W2T[64 * LDA];
    __shared__ float pipb4[4][128];
    __shared__ float b2s[64], w3s[64];

    int tid = threadIdx.x;
    int b = blockIdx.x >> 4;
    int it = blockIdx.x & 15;
    int i0 = it * 4;
    int jt = tid >> 2;
    int kq = tid & 3;

    int w = tid >> 6;
    int l = tid & 63;
    int lr = l & 15;
    int lg = l >> 4;

    float pjreg[32];
    {
        const float* pjrow = pj + (size_t)(b * 64 + w * 16 + lr) * 128;
#pragma unroll
        for (int ks = 0; ks < 4; ++ks) {
            float4 q0 = *reinterpret_cast<const float4*>(pjrow + ks * 32 + lg * 8);
            float4 q1 = *reinterpret_cast<const float4*>(pjrow + ks * 32 + lg * 8 + 4);
            pjreg[ks * 8 + 0] = q0.x; pjreg[ks * 8 + 1] = q0.y;
            pjreg[ks * 8 + 2] = q0.z; pjreg[ks * 8 + 3] = q0.w;
            pjreg[ks * 8 + 4] = q1.x; pjreg[ks * 8 + 5] = q1.y;
            pjreg[ks * 8 + 6] = q1.z; pjreg[ks * 8 + 7] = q1.w;
        }
    }
    if (tid < 128) {
        int row = tid >> 5;
        int c4 = tid & 31;
        float4 v = reinterpret_cast<const float4*>(pi + ((size_t)(b * 64 + i0 + row) * 128))[c4];
        reinterpret_cast<float4*>(&pipb4[row][0])[c4] = v;
    }
    {
        int m = jt;
#pragma unroll
        for (int g = 0; g < 4; ++g) {
            unsigned wb[4];
#pragma unroll
            for (int p = 0; p < 4; ++p) {
                int k = kq * 32 + g * 8 + p * 2;
                wb[p] = (unsigned)f2bf(W2[(size_t)k * 64 + m]) |
                        ((unsigned)f2bf(W2[(size_t)(k + 1) * 64 + m]) << 16);
            }
            *reinterpret_cast<uint4v*>(&W2T[m * LDA + kq * 32 + g * 8]) = *reinterpret_cast<uint4v*>(wb);
        }
    }
    if (tid < 64) {
        b2s[tid] = b2[tid];
        w3s[tid] = W3[tid];
    }
    float b3v = b3[0];
    __syncthreads();

    short8 bfr0[4], bfr1[4];
#pragma unroll
    for (int ks = 0; ks < 4; ++ks) {
        int kb = ks * 32 + lg * 8;
        bfr0[ks] = *reinterpret_cast<const short8*>(&W2T[(0 * 16 + lr) * LDA + kb]);
        bfr1[ks] = *reinterpret_cast<const short8*>(&W2T[(1 * 16 + lr) * LDA + kb]);
    }

    for (int il = 0; il < 4; ++il) {
        f32x4 acc0 = {0.f, 0.f, 0.f, 0.f};
        f32x4 acc1 = {0.f, 0.f, 0.f, 0.f};
        f32x4 acc2 = {0.f, 0.f, 0.f, 0.f};
        f32x4 acc3 = {0.f, 0.f, 0.f, 0.f};
        const float4* prow = reinterpret_cast<const float4*>(&pipb4[il][0]);
#pragma unroll
        for (int ks = 0; ks < 4; ++ks) {
            int kb = ks * 32 + lg * 8;
            float4 pa = prow[ks * 8 + lg * 2];
            float4 pb = prow[ks * 8 + lg * 2 + 1];
            unsigned au[4];
            au[0] = pk2t(fmaxf(pa.x + pjreg[ks * 8 + 0], 0.0f),
                         fmaxf(pa.y + pjreg[ks * 8 + 1], 0.0f));
            au[1] = pk2t(fmaxf(pa.z + pjreg[ks * 8 + 2], 0.0f),
                         fmaxf(pa.w + pjreg[ks * 8 + 3], 0.0f));
            au[2] = pk2t(fmaxf(pb.x + pjreg[ks * 8 + 4], 0.0f),
                         fmaxf(pb.y + pjreg[ks * 8 + 5], 0.0f));
            au[3] = pk2t(fmaxf(pb.z + pjreg[ks * 8 + 6], 0.0f),
                         fmaxf(pb.w + pjreg[ks * 8 + 7], 0.0f));
            short8 afrag = *reinterpret_cast<short8*>(au);
            short8 b2f = *reinterpret_cast<const short8*>(&W2T[(2 * 16 + lr) * LDA + kb]);
            short8 b3f = *reinterpret_cast<const short8*>(&W2T[(3 * 16 + lr) * LDA + kb]);
            acc0 = __builtin_amdgcn_mfma_f32_16x16x32_bf16(afrag, bfr0[ks], acc0, 0, 0, 0);
            acc1 = __builtin_amdgcn_mfma_f32_16x16x32_bf16(afrag, bfr1[ks], acc1, 0, 0, 0);
            acc2 = __builtin_amdgcn_mfma_f32_16x16x32_bf16(afrag, b2f, acc2, 0, 0, 0);
            acc3 = __builtin_amdgcn_mfma_f32_16x16x32_bf16(afrag, b3f, acc3, 0, 0, 0);
        }
        float part[4] = {0.f, 0.f, 0.f, 0.f};
#pragma unroll
        for (int mt = 0; mt < 4; ++mt) {
            int m = mt * 16 + lr;
            float w3 = w3s[m];
            float bb = b2s[m];
            f32x4 a = (mt == 0) ? acc0 : (mt == 1) ? acc1 : (mt == 2) ? acc2 : acc3;
#pragma unroll
            for (int r = 0; r < 4; ++r) {
                float h = fmaxf(a[r] + bb, 0.0f);
                part[r] += h * w3;
            }
        }
#pragma unroll
        for (int r = 0; r < 4; ++r) {
            part[r] += __shfl_xor(part[r], 1);
            part[r] += __shfl_xor(part[r], 2);
            part[r] += __shfl_xor(part[r], 4);
            part[r] += __shfl_xor(part[r], 8);
        }
        if (lr == 0) {
#pragma unroll
            for (int r = 0; r < 4; ++r) {
                int j = w * 16 + lg * 4 + r;
                F[((size_t)b * 64 + i0 + il) * 64 + j] = part[r] + b3v;
            }
        }
    }
}

// ---------------- K4: symmetrize + eye + row-normalize ----------------
__global__ __launch_bounds__(1024) void k4_final(const float* __restrict__ F,
                                                 const float* __restrict__ ap,
                                                 float* __restrict__ out) {
    __shared__ float s[64][65];
    int b = blockIdx.x;
    int tid = threadIdx.x;
    for (int idx = tid; idx < 4096; idx += 1024) {
        s[idx >> 6][idx & 63] = F[(size_t)b * 4096 + idx];
    }
    __syncthreads();
    int wv = tid >> 6, lane = tid & 63;
#pragma unroll
    for (int itr = 0; itr < 4; ++itr) {
        int i = wv * 4 + itr;
        float a_ij = ap[i * 64 + lane];
        float v = 0.5f * a_ij + 0.25f * (s[i][lane] + s[lane][i]);
        v = fmaxf(v, 0.0f);
        if (i == lane) v += 1.0f;
        float sum = v;
        sum += __shfl_xor(sum, 1);
        sum += __shfl_xor(sum, 2);
        sum += __shfl_xor(sum, 4);
        sum += __shfl_xor(sum, 8);
        sum += __shfl_xor(sum, 16);
        sum += __shfl_xor(sum, 32);
        out[(size_t)b * 4096 + i * 64 + lane] = v / (sum + 1e-8f);
    }
}

extern "C" void kernel_launch(void* const* d_in, const int* in_sizes, int n_in,
                              void* d_out, int out_size, void* d_ws, size_t ws_size,
                              hipStream_t stream) {
    const float* tf = (const float*)d_in[0];
    const float* ap = (const float*)d_in[1];
    const float* W1 = (const float*)d_in[2];
    const float* b1 = (const float*)d_in[3];
    const float* W2 = (const float*)d_in[4];
    const float* b2 = (const float*)d_in[5];
    const float* W3 = (const float*)d_in[6];
    const float* b3 = (const float*)d_in[7];
    float* out = (float*)d_out;

    char* ws = (char*)d_ws;
    float* node = (float*)(ws);                          // 2 MB
    float* pi   = (float*)(ws + (size_t)(2 << 20));      // 2 MB (pi + b1)
    float* pj   = (float*)(ws + (size_t)(4 << 20));      // 2 MB
    float* F    = (float*)(ws + (size_t)(6 << 20));      // 1 MB

    k1_mean<<<8192, 256, 0, stream>>>(tf, node);
    k2_proj<<<256, 512, 0, stream>>>(node, W1, b1, pi, pj);
    k3_mlp<<<1024, 256, 0, stream>>>(pi, pj, W2, b2, W3, b3, F);
    k4_final<<<64, 1024, 0, stream>>>(F, ap, out);
}

// Round 15
// 69.715 us; speedup vs baseline: 1.9100x; 1.0159x over previous
//
#include <hip/hip_runtime.h>
#include <stdint.h>
#include <stddef.h>

typedef __attribute__((ext_vector_type(8))) short short8;
typedef __attribute__((ext_vector_type(4))) float f32x4;
typedef __attribute__((ext_vector_type(4))) unsigned uint4v;

__device__ inline unsigned short f2bf(float x) {
    unsigned u = __float_as_uint(x);
    unsigned r = (u + 0x7fffu + ((u >> 16) & 1u)) >> 16;
    return (unsigned short)r;
}

// Pack hi16(lo), hi16(hi) into one dword with a single v_perm_b32 (truncation).
__device__ inline unsigned pk2t(float lo, float hi) {
    return __builtin_amdgcn_perm(__float_as_uint(hi), __float_as_uint(lo), 0x07060302u);
}

// ---------------- K1: node = mean(tf, axis=-1) ----------------
// MEASURED (R10 probe): ~40 us, ~6.7 TB/s = at HBM floor. Do not touch.
__global__ __launch_bounds__(256) void k1_mean(const float* __restrict__ tf,
                                               float* __restrict__ node) {
    int wave = (blockIdx.x * blockDim.x + threadIdx.x) >> 6;  // 0..32767
    int lane = threadIdx.x & 63;
    int half = lane >> 5;
    int c = lane & 31;
    const f32x4* tf4 = reinterpret_cast<const f32x4*>(tf);
    size_t base = (size_t)wave * 8 * 64;

    f32x4 v[8];
#pragma unroll
    for (int k = 0; k < 8; ++k) v[k] = __builtin_nontemporal_load(&tf4[base + (size_t)k * 64 + lane]);

    float s[8];
#pragma unroll
    for (int k = 0; k < 8; ++k) s[k] = (v[k][0] + v[k][1]) + (v[k][2] + v[k][3]);
#pragma unroll
    for (int m = 1; m <= 16; m <<= 1) {
#pragma unroll
        for (int k = 0; k < 8; ++k) s[k] += __shfl_xor(s[k], m);
    }
    if (c == 0) {
#pragma unroll
        for (int k = 0; k < 8; ++k) {
            int rp = wave * 8 + k;
            node[(size_t)rp * 2 + half] = s[k] * (1.0f / 128.0f);
        }
    }
}

// ---------------- K2: pi/pj projection + W2T pre-convert (extra duty) ------
// 512 threads (8 waves) per block; 256 blocks. Blocks 0..15 additionally
// convert W2 (128,64) f32 -> W2T_g (64,128) bf16 (one element per thread).
__global__ __launch_bounds__(512) void k2_proj(const float* __restrict__ node,
                                               const float* __restrict__ W1,
                                               const float* __restrict__ b1,
                                               const float* __restrict__ W2,
                                               float* __restrict__ pi,
                                               float* __restrict__ pj,
                                               unsigned short* __restrict__ w2t_g) {
    const int LP = 136;
    __shared__ unsigned short A_lds[32 * LP];
    __shared__ unsigned short BT[128 * LP];
    __shared__ float b1s[128];

    int tid = threadIdx.x;
    int rblk = blockIdx.x >> 1;
    int half = blockIdx.x & 1;
    int r0 = rblk * 32;

    // Extra duty: W2T_g[m*128+k] = bf16(W2[k*64+m]) for blocks 0..15
    if (blockIdx.x < 16) {
        int idx = blockIdx.x * 512 + tid;   // 0..8191
        int m = idx >> 7, k = idx & 127;
        w2t_g[idx] = f2bf(W2[(size_t)k * 64 + m]);
    }

    {
        int row = tid >> 4;
        int c0 = (tid & 15) * 8;
        const float4* src = reinterpret_cast<const float4*>(node + (size_t)(r0 + row) * 128 + c0);
        float4 va = src[0];
        float4 vb = src[1];
        short8 pk;
        pk[0] = (short)f2bf(va.x); pk[1] = (short)f2bf(va.y);
        pk[2] = (short)f2bf(va.z); pk[3] = (short)f2bf(va.w);
        pk[4] = (short)f2bf(vb.x); pk[5] = (short)f2bf(vb.y);
        pk[6] = (short)f2bf(vb.z); pk[7] = (short)f2bf(vb.w);
        *reinterpret_cast<short8*>(&A_lds[row * LP + c0]) = pk;
    }
    {
        int n = tid & 127;
        int kq = tid >> 7;
        const float* Wbase = W1 + (size_t)half * 128 * 128 + n;
#pragma unroll
        for (int g = 0; g < 4; ++g) {
            int kb = kq * 32 + g * 8;
            short8 pk;
#pragma unroll
            for (int e = 0; e < 8; ++e) pk[e] = (short)f2bf(Wbase[(size_t)(kb + e) * 128]);
            *reinterpret_cast<short8*>(&BT[n * LP + kb]) = pk;
        }
    }
    if (tid < 128) b1s[tid] = b1[tid];
    __syncthreads();

    int w = tid >> 6;
    int l = tid & 63;
    int lr = l & 15;
    int lg = l >> 4;
    int rt = w & 1;
    int cq = w >> 1;

    f32x4 acc[2] = {{0, 0, 0, 0}, {0, 0, 0, 0}};
#pragma unroll
    for (int ks = 0; ks < 4; ++ks) {
        int kb = ks * 32 + lg * 8;
        short8 afrag = *reinterpret_cast<const short8*>(&A_lds[(rt * 16 + lr) * LP + kb]);
#pragma unroll
        for (int nt = 0; nt < 2; ++nt) {
            short8 bfrag = *reinterpret_cast<const short8*>(&BT[(cq * 32 + nt * 16 + lr) * LP + kb]);
            acc[nt] = __builtin_amdgcn_mfma_f32_16x16x32_bf16(afrag, bfrag, acc[nt], 0, 0, 0);
        }
    }
    float* out = half ? pj : pi;
#pragma unroll
    for (int nt = 0; nt < 2; ++nt) {
        int col = cq * 32 + nt * 16 + lr;
        float bias = half ? 0.0f : b1s[col];
#pragma unroll
        for (int r = 0; r < 4; ++r) {
            int row = r0 + rt * 16 + lg * 4 + r;
            out[(size_t)row * 128 + col] = acc[nt][r] + bias;
        }
    }
}

// ---------------- K3: pairwise MLP via MFMA (reg-built A fragments) --------
// W2T staged from pre-converted global bf16 (coalesced b128, L1/L2-hot).
__global__ __launch_bounds__(256) void k3_mlp(const float* __restrict__ pi,
                                              const float* __restrict__ pj,
                                              const unsigned short* __restrict__ w2t_g,
                                              const float* __restrict__ b2,
                                              const float* __restrict__ W3,
                                              const float* __restrict__ b3,
                                              float* __restrict__ F) {
    const int LDA = 136;
    __shared__ unsigned short W2T[64 * LDA];
    __shared__ float pipb4[4][128];
    __shared__ float b2s[64], w3s[64];

    int tid = threadIdx.x;
    int b = blockIdx.x >> 4;
    int it = blockIdx.x & 15;
    int i0 = it * 4;

    int w = tid >> 6;
    int l = tid & 63;
    int lr = l & 15;
    int lg = l >> 4;

    float pjreg[32];
    {
        const float* pjrow = pj + (size_t)(b * 64 + w * 16 + lr) * 128;
#pragma unroll
        for (int ks = 0; ks < 4; ++ks) {
            float4 q0 = *reinterpret_cast<const float4*>(pjrow + ks * 32 + lg * 8);
            float4 q1 = *reinterpret_cast<const float4*>(pjrow + ks * 32 + lg * 8 + 4);
            pjreg[ks * 8 + 0] = q0.x; pjreg[ks * 8 + 1] = q0.y;
            pjreg[ks * 8 + 2] = q0.z; pjreg[ks * 8 + 3] = q0.w;
            pjreg[ks * 8 + 4] = q1.x; pjreg[ks * 8 + 5] = q1.y;
            pjreg[ks * 8 + 6] = q1.z; pjreg[ks * 8 + 7] = q1.w;
        }
    }
    if (tid < 128) {
        int row = tid >> 5;
        int c4 = tid & 31;
        float4 v = reinterpret_cast<const float4*>(pi + ((size_t)(b * 64 + i0 + row) * 128))[c4];
        reinterpret_cast<float4*>(&pipb4[row][0])[c4] = v;
    }
    // W2T stage: coalesced 4x b128 from w2t_g; thread -> row m=tid>>2, q=tid&3
    {
        int m = tid >> 2;
        int q = tid & 3;
        const uint4v* src = reinterpret_cast<const uint4v*>(w2t_g + (size_t)m * 128 + q * 32);
        uint4v* dst = reinterpret_cast<uint4v*>(&W2T[m * LDA + q * 32]);
#pragma unroll
        for (int e = 0; e < 4; ++e) dst[e] = src[e];
    }
    if (tid < 64) {
        b2s[tid] = b2[tid];
        w3s[tid] = W3[tid];
    }
    float b3v = b3[0];
    __syncthreads();

    short8 bfr0[4], bfr1[4];
#pragma unroll
    for (int ks = 0; ks < 4; ++ks) {
        int kb = ks * 32 + lg * 8;
        bfr0[ks] = *reinterpret_cast<const short8*>(&W2T[(0 * 16 + lr) * LDA + kb]);
        bfr1[ks] = *reinterpret_cast<const short8*>(&W2T[(1 * 16 + lr) * LDA + kb]);
    }

    for (int il = 0; il < 4; ++il) {
        f32x4 acc0 = {0.f, 0.f, 0.f, 0.f};
        f32x4 acc1 = {0.f, 0.f, 0.f, 0.f};
        f32x4 acc2 = {0.f, 0.f, 0.f, 0.f};
        f32x4 acc3 = {0.f, 0.f, 0.f, 0.f};
        const float4* prow = reinterpret_cast<const float4*>(&pipb4[il][0]);
#pragma unroll
        for (int ks = 0; ks < 4; ++ks) {
            int kb = ks * 32 + lg * 8;
            float4 pa = prow[ks * 8 + lg * 2];
            float4 pb = prow[ks * 8 + lg * 2 + 1];
            unsigned au[4];
            au[0] = pk2t(fmaxf(pa.x + pjreg[ks * 8 + 0], 0.0f),
                         fmaxf(pa.y + pjreg[ks * 8 + 1], 0.0f));
            au[1] = pk2t(fmaxf(pa.z + pjreg[ks * 8 + 2], 0.0f),
                         fmaxf(pa.w + pjreg[ks * 8 + 3], 0.0f));
            au[2] = pk2t(fmaxf(pb.x + pjreg[ks * 8 + 4], 0.0f),
                         fmaxf(pb.y + pjreg[ks * 8 + 5], 0.0f));
            au[3] = pk2t(fmaxf(pb.z + pjreg[ks * 8 + 6], 0.0f),
                         fmaxf(pb.w + pjreg[ks * 8 + 7], 0.0f));
            short8 afrag = *reinterpret_cast<short8*>(au);
            short8 b2f = *reinterpret_cast<const short8*>(&W2T[(2 * 16 + lr) * LDA + kb]);
            short8 b3f = *reinterpret_cast<const short8*>(&W2T[(3 * 16 + lr) * LDA + kb]);
            acc0 = __builtin_amdgcn_mfma_f32_16x16x32_bf16(afrag, bfr0[ks], acc0, 0, 0, 0);
            acc1 = __builtin_amdgcn_mfma_f32_16x16x32_bf16(afrag, bfr1[ks], acc1, 0, 0, 0);
            acc2 = __builtin_amdgcn_mfma_f32_16x16x32_bf16(afrag, b2f, acc2, 0, 0, 0);
            acc3 = __builtin_amdgcn_mfma_f32_16x16x32_bf16(afrag, b3f, acc3, 0, 0, 0);
        }
        float part[4] = {0.f, 0.f, 0.f, 0.f};
#pragma unroll
        for (int mt = 0; mt < 4; ++mt) {
            int m = mt * 16 + lr;
            float w3 = w3s[m];
            float bb = b2s[m];
            f32x4 a = (mt == 0) ? acc0 : (mt == 1) ? acc1 : (mt == 2) ? acc2 : acc3;
#pragma unroll
            for (int r = 0; r < 4; ++r) {
                float h = fmaxf(a[r] + bb, 0.0f);
                part[r] += h * w3;
            }
        }
#pragma unroll
        for (int r = 0; r < 4; ++r) {
            part[r] += __shfl_xor(part[r], 1);
            part[r] += __shfl_xor(part[r], 2);
            part[r] += __shfl_xor(part[r], 4);
            part[r] += __shfl_xor(part[r], 8);
        }
        if (lr == 0) {
#pragma unroll
            for (int r = 0; r < 4; ++r) {
                int j = w * 16 + lg * 4 + r;
                F[((size_t)b * 64 + i0 + il) * 64 + j] = part[r] + b3v;
            }
        }
    }
}

// ---------------- K4: symmetrize + eye + row-normalize ----------------
__global__ __launch_bounds__(1024) void k4_final(const float* __restrict__ F,
                                                 const float* __restrict__ ap,
                                                 float* __restrict__ out) {
    __shared__ float s[64][65];
    int b = blockIdx.x;
    int tid = threadIdx.x;
    for (int idx = tid; idx < 4096; idx += 1024) {
        s[idx >> 6][idx & 63] = F[(size_t)b * 4096 + idx];
    }
    __syncthreads();
    int wv = tid >> 6, lane = tid & 63;
#pragma unroll
    for (int itr = 0; itr < 4; ++itr) {
        int i = wv * 4 + itr;
        float a_ij = ap[i * 64 + lane];
        float v = 0.5f * a_ij + 0.25f * (s[i][lane] + s[lane][i]);
        v = fmaxf(v, 0.0f);
        if (i == lane) v += 1.0f;
        float sum = v;
        sum += __shfl_xor(sum, 1);
        sum += __shfl_xor(sum, 2);
        sum += __shfl_xor(sum, 4);
        sum += __shfl_xor(sum, 8);
        sum += __shfl_xor(sum, 16);
        sum += __shfl_xor(sum, 32);
        out[(size_t)b * 4096 + i * 64 + lane] = v / (sum + 1e-8f);
    }
}

extern "C" void kernel_launch(void* const* d_in, const int* in_sizes, int n_in,
                              void* d_out, int out_size, void* d_ws, size_t ws_size,
                              hipStream_t stream) {
    const float* tf = (const float*)d_in[0];
    const float* ap = (const float*)d_in[1];
    const float* W1 = (const float*)d_in[2];
    const float* b1 = (const float*)d_in[3];
    const float* W2 = (const float*)d_in[4];
    const float* b2 = (const float*)d_in[5];
    const float* W3 = (const float*)d_in[6];
    const float* b3 = (const float*)d_in[7];
    float* out = (float*)d_out;

    char* ws = (char*)d_ws;
    float* node = (float*)(ws);                              // 2 MB
    float* pi   = (float*)(ws + (size_t)(2 << 20));          // 2 MB (pi + b1)
    float* pj   = (float*)(ws + (size_t)(4 << 20));          // 2 MB
    float* F    = (float*)(ws + (size_t)(6 << 20));          // 1 MB
    unsigned short* w2t_g = (unsigned short*)(ws + (size_t)(7 << 20));  // 16 KB

    k1_mean<<<8192, 256, 0, stream>>>(tf, node);
    k2_proj<<<256, 512, 0, stream>>>(node, W1, b1, W2, pi, pj, w2t_g);
    k3_mlp<<<1024, 256, 0, stream>>>(pi, pj, w2t_g, b2, W3, b3, F);
    k4_final<<<64, 1024, 0, stream>>>(F, ap, out);
}

// Round 17
// 66.602 us; speedup vs baseline: 1.9993x; 1.0467x over previous
//
#include <hip/hip_runtime.h>
#include <stdint.h>
#include <stddef.h>

typedef __attribute__((ext_vector_type(8))) short short8;
typedef __attribute__((ext_vector_type(4))) float f32x4;
typedef __attribute__((ext_vector_type(4))) unsigned uint4v;

__device__ inline unsigned short f2bf(float x) {
    unsigned u = __float_as_uint(x);
    unsigned r = (u + 0x7fffu + ((u >> 16) & 1u)) >> 16;
    return (unsigned short)r;
}

// Pack hi16(lo), hi16(hi) into one dword with a single v_perm_b32 (truncation).
__device__ inline unsigned pk2t(float lo, float hi) {
    return __builtin_amdgcn_perm(__float_as_uint(hi), __float_as_uint(lo), 0x07060302u);
}

// VALU-pipe cross-lane add via DPP (ctrl must be compile-time constant).
template <int CTRL>
__device__ inline float dpp_add(float v) {
    int t = __builtin_amdgcn_update_dpp(0, __float_as_int(v), CTRL, 0xF, 0xF, true);
    return v + __int_as_float(t);
}
// Sum across the 16 lanes of a row; every lane ends with the total.
__device__ inline float row16_sum(float v) {
    v = dpp_add<0xB1>(v);    // quad_perm [1,0,3,2]  (xor 1)
    v = dpp_add<0x4E>(v);    // quad_perm [2,3,0,1]  (xor 2)
    v = dpp_add<0x124>(v);   // row_ror:4
    v = dpp_add<0x128>(v);   // row_ror:8
    return v;
}

// ---------------- K1: node = mean(tf, axis=-1) ----------------
// MEASURED (R10 probe): ~40 us, ~6.7 TB/s = at HBM floor. Do not touch.
__global__ __launch_bounds__(256) void k1_mean(const float* __restrict__ tf,
                                               float* __restrict__ node) {
    int wave = (blockIdx.x * blockDim.x + threadIdx.x) >> 6;  // 0..32767
    int lane = threadIdx.x & 63;
    int half = lane >> 5;
    int c = lane & 31;
    const f32x4* tf4 = reinterpret_cast<const f32x4*>(tf);
    size_t base = (size_t)wave * 8 * 64;

    f32x4 v[8];
#pragma unroll
    for (int k = 0; k < 8; ++k) v[k] = __builtin_nontemporal_load(&tf4[base + (size_t)k * 64 + lane]);

    float s[8];
#pragma unroll
    for (int k = 0; k < 8; ++k) s[k] = (v[k][0] + v[k][1]) + (v[k][2] + v[k][3]);
#pragma unroll
    for (int m = 1; m <= 16; m <<= 1) {
#pragma unroll
        for (int k = 0; k < 8; ++k) s[k] += __shfl_xor(s[k], m);
    }
    if (c == 0) {
#pragma unroll
        for (int k = 0; k < 8; ++k) {
            int rp = wave * 8 + k;
            node[(size_t)rp * 2 + half] = s[k] * (1.0f / 128.0f);
        }
    }
}

// ---------------- K2: pi/pj projection + W2T pre-convert (extra duty) ------
__global__ __launch_bounds__(512) void k2_proj(const float* __restrict__ node,
                                               const float* __restrict__ W1,
                                               const float* __restrict__ b1,
                                               const float* __restrict__ W2,
                                               float* __restrict__ pi,
                                               float* __restrict__ pj,
                                               unsigned short* __restrict__ w2t_g) {
    const int LP = 136;
    __shared__ unsigned short A_lds[32 * LP];
    __shared__ unsigned short BT[128 * LP];
    __shared__ float b1s[128];

    int tid = threadIdx.x;
    int rblk = blockIdx.x >> 1;
    int half = blockIdx.x & 1;
    int r0 = rblk * 32;

    if (blockIdx.x < 16) {
        int idx = blockIdx.x * 512 + tid;   // 0..8191
        int m = idx >> 7, k = idx & 127;
        w2t_g[idx] = f2bf(W2[(size_t)k * 64 + m]);
    }

    {
        int row = tid >> 4;
        int c0 = (tid & 15) * 8;
        const float4* src = reinterpret_cast<const float4*>(node + (size_t)(r0 + row) * 128 + c0);
        float4 va = src[0];
        float4 vb = src[1];
        short8 pk;
        pk[0] = (short)f2bf(va.x); pk[1] = (short)f2bf(va.y);
        pk[2] = (short)f2bf(va.z); pk[3] = (short)f2bf(va.w);
        pk[4] = (short)f2bf(vb.x); pk[5] = (short)f2bf(vb.y);
        pk[6] = (short)f2bf(vb.z); pk[7] = (short)f2bf(vb.w);
        *reinterpret_cast<short8*>(&A_lds[row * LP + c0]) = pk;
    }
    {
        int n = tid & 127;
        int kq = tid >> 7;
        const float* Wbase = W1 + (size_t)half * 128 * 128 + n;
#pragma unroll
        for (int g = 0; g < 4; ++g) {
            int kb = kq * 32 + g * 8;
            short8 pk;
#pragma unroll
            for (int e = 0; e < 8; ++e) pk[e] = (short)f2bf(Wbase[(size_t)(kb + e) * 128]);
            *reinterpret_cast<short8*>(&BT[n * LP + kb]) = pk;
        }
    }
    if (tid < 128) b1s[tid] = b1[tid];
    __syncthreads();

    int w = tid >> 6;
    int l = tid & 63;
    int lr = l & 15;
    int lg = l >> 4;
    int rt = w & 1;
    int cq = w >> 1;

    f32x4 acc[2] = {{0, 0, 0, 0}, {0, 0, 0, 0}};
#pragma unroll
    for (int ks = 0; ks < 4; ++ks) {
        int kb = ks * 32 + lg * 8;
        short8 afrag = *reinterpret_cast<const short8*>(&A_lds[(rt * 16 + lr) * LP + kb]);
#pragma unroll
        for (int nt = 0; nt < 2; ++nt) {
            short8 bfrag = *reinterpret_cast<const short8*>(&BT[(cq * 32 + nt * 16 + lr) * LP + kb]);
            acc[nt] = __builtin_amdgcn_mfma_f32_16x16x32_bf16(afrag, bfrag, acc[nt], 0, 0, 0);
        }
    }
    float* out = half ? pj : pi;
#pragma unroll
    for (int nt = 0; nt < 2; ++nt) {
        int col = cq * 32 + nt * 16 + lr;
        float bias = half ? 0.0f : b1s[col];
#pragma unroll
        for (int r = 0; r < 4; ++r) {
            int row = r0 + rt * 16 + lg * 4 + r;
            out[(size_t)row * 128 + col] = acc[nt][r] + bias;
        }
    }
}

// ---------------- K3: pairwise MLP via MFMA (reg A-frags, full W2T hoist) --
// Grid 512 = (b, it of 8 i's). All 16 W2T fragments in regs; epilogue
// reduce via DPP (VALU pipe). In-loop LDS: 8 pipb b128 reads per il only.
__global__ __launch_bounds__(256) void k3_mlp(const float* __restrict__ pi,
                                              const float* __restrict__ pj,
                                              const unsigned short* __restrict__ w2t_g,
                                              const float* __restrict__ b2,
                                              const float* __restrict__ W3,
                                              const float* __restrict__ b3,
                                              float* __restrict__ F) {
    const int LDA = 136;
    __shared__ unsigned short W2T[64 * LDA];
    __shared__ float pipb8[8][128];
    __shared__ float b2s[64], w3s[64];

    int tid = threadIdx.x;
    int b = blockIdx.x >> 3;
    int it = blockIdx.x & 7;
    int i0 = it * 8;

    int w = tid >> 6;
    int l = tid & 63;
    int lr = l & 15;
    int lg = l >> 4;

    float pjreg[32];
    {
        const float* pjrow = pj + (size_t)(b * 64 + w * 16 + lr) * 128;
#pragma unroll
        for (int ks = 0; ks < 4; ++ks) {
            float4 q0 = *reinterpret_cast<const float4*>(pjrow + ks * 32 + lg * 8);
            float4 q1 = *reinterpret_cast<const float4*>(pjrow + ks * 32 + lg * 8 + 4);
            pjreg[ks * 8 + 0] = q0.x; pjreg[ks * 8 + 1] = q0.y;
            pjreg[ks * 8 + 2] = q0.z; pjreg[ks * 8 + 3] = q0.w;
            pjreg[ks * 8 + 4] = q1.x; pjreg[ks * 8 + 5] = q1.y;
            pjreg[ks * 8 + 6] = q1.z; pjreg[ks * 8 + 7] = q1.w;
        }
    }
    // pi rows i0..i0+7 -> LDS (8x128 f32); 256 threads x float4
    {
        int row = tid >> 5;
        int c4 = tid & 31;
        float4 v = reinterpret_cast<const float4*>(pi + ((size_t)(b * 64 + i0 + row) * 128))[c4];
        reinterpret_cast<float4*>(&pipb8[row][0])[c4] = v;
    }
    // W2T stage: coalesced b128 from w2t_g
    {
        int m = tid >> 2;
        int q = tid & 3;
        const uint4v* src = reinterpret_cast<const uint4v*>(w2t_g + (size_t)m * 128 + q * 32);
        uint4v* dst = reinterpret_cast<uint4v*>(&W2T[m * LDA + q * 32]);
#pragma unroll
        for (int e = 0; e < 4; ++e) dst[e] = src[e];
    }
    if (tid < 64) {
        b2s[tid] = b2[tid];
        w3s[tid] = W3[tid];
    }
    float b3v = b3[0];
    __syncthreads();

    // Hoist ALL W2T fragments (iteration-invariant): 16 x short8 = 64 VGPR
    short8 bfr[4][4];
#pragma unroll
    for (int ks = 0; ks < 4; ++ks) {
        int kb = ks * 32 + lg * 8;
#pragma unroll
        for (int nt = 0; nt < 4; ++nt)
            bfr[ks][nt] = *reinterpret_cast<const short8*>(&W2T[(nt * 16 + lr) * LDA + kb]);
    }

#pragma unroll 2
    for (int il = 0; il < 8; ++il) {
        f32x4 acc0 = {0.f, 0.f, 0.f, 0.f};
        f32x4 acc1 = {0.f, 0.f, 0.f, 0.f};
        f32x4 acc2 = {0.f, 0.f, 0.f, 0.f};
        f32x4 acc3 = {0.f, 0.f, 0.f, 0.f};
        const float4* prow = reinterpret_cast<const float4*>(&pipb8[il][0]);
#pragma unroll
        for (int ks = 0; ks < 4; ++ks) {
            float4 pa = prow[ks * 8 + lg * 2];
            float4 pb = prow[ks * 8 + lg * 2 + 1];
            unsigned au[4];
            au[0] = pk2t(fmaxf(pa.x + pjreg[ks * 8 + 0], 0.0f),
                         fmaxf(pa.y + pjreg[ks * 8 + 1], 0.0f));
            au[1] = pk2t(fmaxf(pa.z + pjreg[ks * 8 + 2], 0.0f),
                         fmaxf(pa.w + pjreg[ks * 8 + 3], 0.0f));
            au[2] = pk2t(fmaxf(pb.x + pjreg[ks * 8 + 4], 0.0f),
                         fmaxf(pb.y + pjreg[ks * 8 + 5], 0.0f));
            au[3] = pk2t(fmaxf(pb.z + pjreg[ks * 8 + 6], 0.0f),
                         fmaxf(pb.w + pjreg[ks * 8 + 7], 0.0f));
            short8 afrag = *reinterpret_cast<short8*>(au);
            acc0 = __builtin_amdgcn_mfma_f32_16x16x32_bf16(afrag, bfr[ks][0], acc0, 0, 0, 0);
            acc1 = __builtin_amdgcn_mfma_f32_16x16x32_bf16(afrag, bfr[ks][1], acc1, 0, 0, 0);
            acc2 = __builtin_amdgcn_mfma_f32_16x16x32_bf16(afrag, bfr[ks][2], acc2, 0, 0, 0);
            acc3 = __builtin_amdgcn_mfma_f32_16x16x32_bf16(afrag, bfr[ks][3], acc3, 0, 0, 0);
        }
        float part[4] = {0.f, 0.f, 0.f, 0.f};
#pragma unroll
        for (int mt = 0; mt < 4; ++mt) {
            int m = mt * 16 + lr;
            float w3 = w3s[m];
            float bb = b2s[m];
            f32x4 a = (mt == 0) ? acc0 : (mt == 1) ? acc1 : (mt == 2) ? acc2 : acc3;
#pragma unroll
            for (int r = 0; r < 4; ++r) {
                float h = fmaxf(a[r] + bb, 0.0f);
                part[r] += h * w3;
            }
        }
#pragma unroll
        for (int r = 0; r < 4; ++r) part[r] = row16_sum(part[r]);
        if (lr == 0) {
#pragma unroll
            for (int r = 0; r < 4; ++r) {
                int j = w * 16 + lg * 4 + r;
                F[((size_t)b * 64 + i0 + il) * 64 + j] = part[r] + b3v;
            }
        }
    }
}

// ---------------- K4: symmetrize + eye + row-normalize ----------------
__global__ __launch_bounds__(1024) void k4_final(const float* __restrict__ F,
                                                 const float* __restrict__ ap,
                                                 float* __restrict__ out) {
    __shared__ float s[64][65];
    int b = blockIdx.x;
    int tid = threadIdx.x;
    for (int idx = tid; idx < 4096; idx += 1024) {
        s[idx >> 6][idx & 63] = F[(size_t)b * 4096 + idx];
    }
    __syncthreads();
    int wv = tid >> 6, lane = tid & 63;
#pragma unroll
    for (int itr = 0; itr < 4; ++itr) {
        int i = wv * 4 + itr;
        float a_ij = ap[i * 64 + lane];
        float v = 0.5f * a_ij + 0.25f * (s[i][lane] + s[lane][i]);
        v = fmaxf(v, 0.0f);
        if (i == lane) v += 1.0f;
        float sum = v;
        sum += __shfl_xor(sum, 1);
        sum += __shfl_xor(sum, 2);
        sum += __shfl_xor(sum, 4);
        sum += __shfl_xor(sum, 8);
        sum += __shfl_xor(sum, 16);
        sum += __shfl_xor(sum, 32);
        out[(size_t)b * 4096 + i * 64 + lane] = v / (sum + 1e-8f);
    }
}

extern "C" void kernel_launch(void* const* d_in, const int* in_sizes, int n_in,
                              void* d_out, int out_size, void* d_ws, size_t ws_size,
                              hipStream_t stream) {
    const float* tf = (const float*)d_in[0];
    const float* ap = (const float*)d_in[1];
    const float* W1 = (const float*)d_in[2];
    const float* b1 = (const float*)d_in[3];
    const float* W2 = (const float*)d_in[4];
    const float* b2 = (const float*)d_in[5];
    const float* W3 = (const float*)d_in[6];
    const float* b3 = (const float*)d_in[7];
    float* out = (float*)d_out;

    char* ws = (char*)d_ws;
    float* node = (float*)(ws);                              // 2 MB
    float* pi   = (float*)(ws + (size_t)(2 << 20));          // 2 MB (pi + b1)
    float* pj   = (float*)(ws + (size_t)(4 << 20));          // 2 MB
    float* F    = (float*)(ws + (size_t)(6 << 20));          // 1 MB
    unsigned short* w2t_g = (unsigned short*)(ws + (size_t)(7 << 20));  // 16 KB

    k1_mean<<<8192, 256, 0, stream>>>(tf, node);
    k2_proj<<<256, 512, 0, stream>>>(node, W1, b1, W2, pi, pj, w2t_g);
    k3_mlp<<<512, 256, 0, stream>>>(pi, pj, w2t_g, b2, W3, b3, F);
    k4_final<<<64, 1024, 0, stream>>>(F, ap, out);
}

// Round 18
// 65.559 us; speedup vs baseline: 2.0311x; 1.0159x over previous
//
#include <hip/hip_runtime.h>
#include <stdint.h>
#include <stddef.h>

typedef __attribute__((ext_vector_type(8))) short short8;
typedef __attribute__((ext_vector_type(4))) float f32x4;
typedef __attribute__((ext_vector_type(4))) unsigned uint4v;

__device__ inline unsigned short f2bf(float x) {
    unsigned u = __float_as_uint(x);
    unsigned r = (u + 0x7fffu + ((u >> 16) & 1u)) >> 16;
    return (unsigned short)r;
}

// Pack hi16(lo), hi16(hi) into one dword with a single v_perm_b32 (truncation).
__device__ inline unsigned pk2t(float lo, float hi) {
    return __builtin_amdgcn_perm(__float_as_uint(hi), __float_as_uint(lo), 0x07060302u);
}

// VALU-pipe cross-lane add via DPP (ctrl must be compile-time constant).
template <int CTRL>
__device__ inline float dpp_add(float v) {
    int t = __builtin_amdgcn_update_dpp(0, __float_as_int(v), CTRL, 0xF, 0xF, true);
    return v + __int_as_float(t);
}
// Sum across the 16 lanes of a row; every lane ends with the total.
__device__ inline float row16_sum(float v) {
    v = dpp_add<0xB1>(v);    // quad_perm [1,0,3,2]  (xor 1)
    v = dpp_add<0x4E>(v);    // quad_perm [2,3,0,1]  (xor 2)
    v = dpp_add<0x124>(v);   // row_ror:4
    v = dpp_add<0x128>(v);   // row_ror:8
    return v;
}

// ---------------- K1: node = mean(tf, axis=-1) + W1T pre-convert -----------
// MEASURED (R10 probe): ~40 us, ~6.7 TB/s = at HBM floor.
// Extra duty: blocks 0..63 convert W1 -> w1t_g[c*128+k] = bf16(W1[ch*128+k][n])
// (c = ch*128+n); 2 elements/thread, hidden under the HBM stream.
__global__ __launch_bounds__(256) void k1_mean(const float* __restrict__ tf,
                                               const float* __restrict__ W1,
                                               float* __restrict__ node,
                                               unsigned short* __restrict__ w1t_g) {
    if (blockIdx.x < 64) {
        int base = blockIdx.x * 512 + threadIdx.x * 2;
#pragma unroll
        for (int e = 0; e < 2; ++e) {
            int idx = base + e;
            int c = idx >> 7, k = idx & 127;
            int ch = c >> 7, n = c & 127;
            w1t_g[idx] = f2bf(W1[(size_t)ch * 16384 + (size_t)k * 128 + n]);
        }
    }
    int wave = (blockIdx.x * blockDim.x + threadIdx.x) >> 6;  // 0..32767
    int lane = threadIdx.x & 63;
    int half = lane >> 5;
    int c = lane & 31;
    const f32x4* tf4 = reinterpret_cast<const f32x4*>(tf);
    size_t base = (size_t)wave * 8 * 64;

    f32x4 v[8];
#pragma unroll
    for (int k = 0; k < 8; ++k) v[k] = __builtin_nontemporal_load(&tf4[base + (size_t)k * 64 + lane]);

    float s[8];
#pragma unroll
    for (int k = 0; k < 8; ++k) s[k] = (v[k][0] + v[k][1]) + (v[k][2] + v[k][3]);
#pragma unroll
    for (int m = 1; m <= 16; m <<= 1) {
#pragma unroll
        for (int k = 0; k < 8; ++k) s[k] += __shfl_xor(s[k], m);
    }
    if (c == 0) {
#pragma unroll
        for (int k = 0; k < 8; ++k) {
            int rp = wave * 8 + k;
            node[(size_t)rp * 2 + half] = s[k] * (1.0f / 128.0f);
        }
    }
}

// ---------------- K2: pi/pj projection (coalesced BT stage) ----------------
// 512 blocks (16 rows x half) x 512 threads = 2 blocks/CU. BT staged with
// coalesced b128 loads from pre-converted w1t_g (L2-hot). Blocks 0..15 also
// pre-convert W2T (extra duty).
__global__ __launch_bounds__(512) void k2_proj(const float* __restrict__ node,
                                               const unsigned short* __restrict__ w1t_g,
                                               const float* __restrict__ b1,
                                               const float* __restrict__ W2,
                                               float* __restrict__ pi,
                                               float* __restrict__ pj,
                                               unsigned short* __restrict__ w2t_g) {
    const int LP = 136;
    __shared__ unsigned short A_lds[16 * LP];
    __shared__ unsigned short BT[128 * LP];
    __shared__ float b1s[128];

    int tid = threadIdx.x;
    int rblk = blockIdx.x >> 1;
    int half = blockIdx.x & 1;
    int r0 = rblk * 16;

    if (blockIdx.x < 16) {
        int idx = blockIdx.x * 512 + tid;   // 0..8191
        int m = idx >> 7, k = idx & 127;
        w2t_g[idx] = f2bf(W2[(size_t)k * 64 + m]);
    }

    // Stage A: 16 rows x 128 cols; thread -> row = t>>5, 4 cols
    {
        int row = tid >> 5;
        int c0 = (tid & 31) * 4;
        float4 v = *reinterpret_cast<const float4*>(node + (size_t)(r0 + row) * 128 + c0);
        unsigned wb[2];
        wb[0] = (unsigned)f2bf(v.x) | ((unsigned)f2bf(v.y) << 16);
        wb[1] = (unsigned)f2bf(v.z) | ((unsigned)f2bf(v.w) << 16);
        *reinterpret_cast<uint2*>(&A_lds[row * LP + c0]) = *reinterpret_cast<uint2*>(wb);
    }
    // Stage BT: coalesced from w1t_g; thread -> n = t>>2, q = t&3 (32 cols)
    {
        int n = tid >> 2;
        int q = tid & 3;
        const uint4v* src = reinterpret_cast<const uint4v*>(w1t_g + ((size_t)(half * 128 + n) * 128 + q * 32));
        uint4v* dst = reinterpret_cast<uint4v*>(&BT[n * LP + q * 32]);
#pragma unroll
        for (int e = 0; e < 4; ++e) dst[e] = src[e];
    }
    if (tid < 128) b1s[tid] = b1[tid];
    __syncthreads();

    int w = tid >> 6;      // 0..7 -> col-sixteenth
    int l = tid & 63;
    int lr = l & 15;
    int lg = l >> 4;

    f32x4 acc = {0, 0, 0, 0};
#pragma unroll
    for (int ks = 0; ks < 4; ++ks) {
        int kb = ks * 32 + lg * 8;
        short8 afrag = *reinterpret_cast<const short8*>(&A_lds[lr * LP + kb]);
        short8 bfrag = *reinterpret_cast<const short8*>(&BT[(w * 16 + lr) * LP + kb]);
        acc = __builtin_amdgcn_mfma_f32_16x16x32_bf16(afrag, bfrag, acc, 0, 0, 0);
    }
    float* out = half ? pj : pi;
    int col = w * 16 + lr;
    float bias = half ? 0.0f : b1s[col];
#pragma unroll
    for (int r = 0; r < 4; ++r) {
        int row = r0 + lg * 4 + r;
        out[(size_t)row * 128 + col] = acc[r] + bias;
    }
}

// ---------------- K3: pairwise MLP via MFMA (reg A-frags, full W2T hoist) --
// Grid 512 = (b, it of 8 i's). All 16 W2T fragments in regs; epilogue
// reduce via DPP (VALU pipe). In-loop LDS: 8 pipb b128 reads per il only.
__global__ __launch_bounds__(256) void k3_mlp(const float* __restrict__ pi,
                                              const float* __restrict__ pj,
                                              const unsigned short* __restrict__ w2t_g,
                                              const float* __restrict__ b2,
                                              const float* __restrict__ W3,
                                              const float* __restrict__ b3,
                                              float* __restrict__ F) {
    const int LDA = 136;
    __shared__ unsigned short W2T[64 * LDA];
    __shared__ float pipb8[8][128];
    __shared__ float b2s[64], w3s[64];

    int tid = threadIdx.x;
    int b = blockIdx.x >> 3;
    int it = blockIdx.x & 7;
    int i0 = it * 8;

    int w = tid >> 6;
    int l = tid & 63;
    int lr = l & 15;
    int lg = l >> 4;

    float pjreg[32];
    {
        const float* pjrow = pj + (size_t)(b * 64 + w * 16 + lr) * 128;
#pragma unroll
        for (int ks = 0; ks < 4; ++ks) {
            float4 q0 = *reinterpret_cast<const float4*>(pjrow + ks * 32 + lg * 8);
            float4 q1 = *reinterpret_cast<const float4*>(pjrow + ks * 32 + lg * 8 + 4);
            pjreg[ks * 8 + 0] = q0.x; pjreg[ks * 8 + 1] = q0.y;
            pjreg[ks * 8 + 2] = q0.z; pjreg[ks * 8 + 3] = q0.w;
            pjreg[ks * 8 + 4] = q1.x; pjreg[ks * 8 + 5] = q1.y;
            pjreg[ks * 8 + 6] = q1.z; pjreg[ks * 8 + 7] = q1.w;
        }
    }
    // pi rows i0..i0+7 -> LDS (8x128 f32); 256 threads x float4
    {
        int row = tid >> 5;
        int c4 = tid & 31;
        float4 v = reinterpret_cast<const float4*>(pi + ((size_t)(b * 64 + i0 + row) * 128))[c4];
        reinterpret_cast<float4*>(&pipb8[row][0])[c4] = v;
    }
    // W2T stage: coalesced b128 from w2t_g
    {
        int m = tid >> 2;
        int q = tid & 3;
        const uint4v* src = reinterpret_cast<const uint4v*>(w2t_g + (size_t)m * 128 + q * 32);
        uint4v* dst = reinterpret_cast<uint4v*>(&W2T[m * LDA + q * 32]);
#pragma unroll
        for (int e = 0; e < 4; ++e) dst[e] = src[e];
    }
    if (tid < 64) {
        b2s[tid] = b2[tid];
        w3s[tid] = W3[tid];
    }
    float b3v = b3[0];
    __syncthreads();

    // Hoist ALL W2T fragments (iteration-invariant): 16 x short8 = 64 VGPR
    short8 bfr[4][4];
#pragma unroll
    for (int ks = 0; ks < 4; ++ks) {
        int kb = ks * 32 + lg * 8;
#pragma unroll
        for (int nt = 0; nt < 4; ++nt)
            bfr[ks][nt] = *reinterpret_cast<const short8*>(&W2T[(nt * 16 + lr) * LDA + kb]);
    }

#pragma unroll 2
    for (int il = 0; il < 8; ++il) {
        f32x4 acc0 = {0.f, 0.f, 0.f, 0.f};
        f32x4 acc1 = {0.f, 0.f, 0.f, 0.f};
        f32x4 acc2 = {0.f, 0.f, 0.f, 0.f};
        f32x4 acc3 = {0.f, 0.f, 0.f, 0.f};
        const float4* prow = reinterpret_cast<const float4*>(&pipb8[il][0]);
#pragma unroll
        for (int ks = 0; ks < 4; ++ks) {
            float4 pa = prow[ks * 8 + lg * 2];
            float4 pb = prow[ks * 8 + lg * 2 + 1];
            unsigned au[4];
            au[0] = pk2t(fmaxf(pa.x + pjreg[ks * 8 + 0], 0.0f),
                         fmaxf(pa.y + pjreg[ks * 8 + 1], 0.0f));
            au[1] = pk2t(fmaxf(pa.z + pjreg[ks * 8 + 2], 0.0f),
                         fmaxf(pa.w + pjreg[ks * 8 + 3], 0.0f));
            au[2] = pk2t(fmaxf(pb.x + pjreg[ks * 8 + 4], 0.0f),
                         fmaxf(pb.y + pjreg[ks * 8 + 5], 0.0f));
            au[3] = pk2t(fmaxf(pb.z + pjreg[ks * 8 + 6], 0.0f),
                         fmaxf(pb.w + pjreg[ks * 8 + 7], 0.0f));
            short8 afrag = *reinterpret_cast<short8*>(au);
            acc0 = __builtin_amdgcn_mfma_f32_16x16x32_bf16(afrag, bfr[ks][0], acc0, 0, 0, 0);
            acc1 = __builtin_amdgcn_mfma_f32_16x16x32_bf16(afrag, bfr[ks][1], acc1, 0, 0, 0);
            acc2 = __builtin_amdgcn_mfma_f32_16x16x32_bf16(afrag, bfr[ks][2], acc2, 0, 0, 0);
            acc3 = __builtin_amdgcn_mfma_f32_16x16x32_bf16(afrag, bfr[ks][3], acc3, 0, 0, 0);
        }
        float part[4] = {0.f, 0.f, 0.f, 0.f};
#pragma unroll
        for (int mt = 0; mt < 4; ++mt) {
            int m = mt * 16 + lr;
            float w3 = w3s[m];
            float bb = b2s[m];
            f32x4 a = (mt == 0) ? acc0 : (mt == 1) ? acc1 : (mt == 2) ? acc2 : acc3;
#pragma unroll
            for (int r = 0; r < 4; ++r) {
                float h = fmaxf(a[r] + bb, 0.0f);
                part[r] += h * w3;
            }
        }
#pragma unroll
        for (int r = 0; r < 4; ++r) part[r] = row16_sum(part[r]);
        if (lr == 0) {
#pragma unroll
            for (int r = 0; r < 4; ++r) {
                int j = w * 16 + lg * 4 + r;
                F[((size_t)b * 64 + i0 + il) * 64 + j] = part[r] + b3v;
            }
        }
    }
}

// ---------------- K4: symmetrize + eye + row-normalize ----------------
// 128 blocks (2 per batch; each computes 32 rows, loads full F_b).
__global__ __launch_bounds__(512) void k4_final(const float* __restrict__ F,
                                                const float* __restrict__ ap,
                                                float* __restrict__ out) {
    __shared__ float s[64][65];
    int b = blockIdx.x >> 1;
    int rh = (blockIdx.x & 1) * 32;
    int tid = threadIdx.x;
    for (int idx = tid; idx < 4096; idx += 512) {
        s[idx >> 6][idx & 63] = F[(size_t)b * 4096 + idx];
    }
    __syncthreads();
    int wv = tid >> 6, lane = tid & 63;
#pragma unroll
    for (int itr = 0; itr < 4; ++itr) {
        int i = rh + wv * 4 + itr;
        float a_ij = ap[i * 64 + lane];
        float v = 0.5f * a_ij + 0.25f * (s[i][lane] + s[lane][i]);
        v = fmaxf(v, 0.0f);
        if (i == lane) v += 1.0f;
        float sum = v;
        sum += __shfl_xor(sum, 1);
        sum += __shfl_xor(sum, 2);
        sum += __shfl_xor(sum, 4);
        sum += __shfl_xor(sum, 8);
        sum += __shfl_xor(sum, 16);
        sum += __shfl_xor(sum, 32);
        out[(size_t)b * 4096 + i * 64 + lane] = v / (sum + 1e-8f);
    }
}

extern "C" void kernel_launch(void* const* d_in, const int* in_sizes, int n_in,
                              void* d_out, int out_size, void* d_ws, size_t ws_size,
                              hipStream_t stream) {
    const float* tf = (const float*)d_in[0];
    const float* ap = (const float*)d_in[1];
    const float* W1 = (const float*)d_in[2];
    const float* b1 = (const float*)d_in[3];
    const float* W2 = (const float*)d_in[4];
    const float* b2 = (const float*)d_in[5];
    const float* W3 = (const float*)d_in[6];
    const float* b3 = (const float*)d_in[7];
    float* out = (float*)d_out;

    char* ws = (char*)d_ws;
    float* node = (float*)(ws);                              // 2 MB
    float* pi   = (float*)(ws + (size_t)(2 << 20));          // 2 MB (pi + b1)
    float* pj   = (float*)(ws + (size_t)(4 << 20));          // 2 MB
    float* F    = (float*)(ws + (size_t)(6 << 20));          // 1 MB
    unsigned short* w2t_g = (unsigned short*)(ws + (size_t)(7 << 20));            // 16 KB
    unsigned short* w1t_g = (unsigned short*)(ws + (size_t)(7 << 20) + 65536);    // 64 KB

    k1_mean<<<8192, 256, 0, stream>>>(tf, W1, node, w1t_g);
    k2_proj<<<512, 512, 0, stream>>>(node, w1t_g, b1, W2, pi, pj, w2t_g);
    k3_mlp<<<512, 256, 0, stream>>>(pi, pj, w2t_g, b2, W3, b3, F);
    k4_final<<<128, 512, 0, stream>>>(F, ap, out);
}